// Round 1
// baseline (1301.636 us; speedup 1.0000x reference)
//
#include <hip/hip_runtime.h>
#include <hip/hip_bf16.h>
#include <cstdint>

#define NNODES 100000
#define NEDGES 1600000
#define NGRAPHS 64
#define DIM 128

__device__ inline unsigned fkey(float f) {
  unsigned b = __float_as_uint(f);
  return (b & 0x80000000u) ? ~b : (b | 0x80000000u);
}
__device__ inline float fdecode(unsigned k) {
  unsigned b = (k & 0x80000000u) ? (k & 0x7FFFFFFFu) : ~k;
  return __uint_as_float(b);
}

// h[i][d] = emb_type[node_type[i]][d] + emb_inv[ninv[i]][d]
__global__ void encoder_kernel(const int* __restrict__ nt, const int* __restrict__ ninv,
                               const float* __restrict__ et, const float* __restrict__ ei,
                               float* __restrict__ h) {
  int idx = blockIdx.x * blockDim.x + threadIdx.x;
  if (idx >= NNODES * DIM) return;
  int i = idx >> 7, d = idx & 127;
  h[idx] = et[nt[i] * DIM + d] + ei[ninv[i] * DIM + d];
}

__global__ void count_kernel(const int* __restrict__ dst, int* __restrict__ cnt) {
  int e = blockIdx.x * blockDim.x + threadIdx.x;
  if (e < NEDGES) atomicAdd(&cnt[dst[e]], 1);
}

__global__ void dinv_kernel(const int* __restrict__ cnt, float* __restrict__ dinv) {
  int i = blockIdx.x * blockDim.x + threadIdx.x;
  if (i < NNODES) dinv[i] = rsqrtf((float)cnt[i] + 1.0f);
}

// single-block exclusive scan of cnt -> offs (and copy to cursor)
__global__ __launch_bounds__(1024) void scan_kernel(const int* __restrict__ cnt,
                                                    int* __restrict__ offs,
                                                    int* __restrict__ cursor) {
  __shared__ int buf[1024];
  int tid = threadIdx.x;
  int carry = 0;
  for (int base = 0; base < NNODES; base += 1024) {
    int i = base + tid;
    int v = (i < NNODES) ? cnt[i] : 0;
    buf[tid] = v;
    __syncthreads();
    for (int o = 1; o < 1024; o <<= 1) {
      int t = (tid >= o) ? buf[tid - o] : 0;
      __syncthreads();
      buf[tid] += t;
      __syncthreads();
    }
    int excl = carry + buf[tid] - v;
    if (i < NNODES) { offs[i] = excl; cursor[i] = excl; }
    carry += buf[1023];
    __syncthreads();  // protect buf before next chunk overwrites
  }
  if (tid == 0) offs[NNODES] = carry;
}

__global__ void fill_kernel(const int* __restrict__ src, const int* __restrict__ dst,
                            int* __restrict__ cursor, int* __restrict__ csr_src) {
  int e = blockIdx.x * blockDim.x + threadIdx.x;
  if (e < NEDGES) {
    int pos = atomicAdd(&cursor[dst[e]], 1);
    csr_src[pos] = src[e];
  }
}

// xw = h @ W  (f32, W transposed+padded in LDS, 8 rows of h staged per iter)
__global__ __launch_bounds__(256) void gemm_kernel(const float* __restrict__ h,
                                                   const float* __restrict__ W,
                                                   float* __restrict__ out, int n) {
  __shared__ float Wt[128 * 132];  // Wt[c*132+k] = W[k*128+c]
  __shared__ float hs[8 * 128];
  for (int idx = threadIdx.x; idx < 128 * 128; idx += 256) {
    int k = idx >> 7, c = idx & 127;
    Wt[c * 132 + k] = W[idx];
  }
  int col = threadIdx.x & 127;
  int half = threadIdx.x >> 7;  // 0/1
  for (int base = blockIdx.x * 8; base < n; base += gridDim.x * 8) {
    __syncthreads();  // protects hs reuse + first-iter Wt staging
    // stage 8 rows (8*128 floats = 256 float4, one per thread)
    ((float4*)hs)[threadIdx.x] = ((const float4*)(h + (size_t)base * DIM))[threadIdx.x];
    __syncthreads();
    float acc0 = 0.f, acc1 = 0.f, acc2 = 0.f, acc3 = 0.f;
    for (int k = 0; k < 128; k += 4) {
      float4 w = *(const float4*)&Wt[col * 132 + k];
      float4 h0 = *(const float4*)&hs[(half * 4 + 0) * 128 + k];
      float4 h1 = *(const float4*)&hs[(half * 4 + 1) * 128 + k];
      float4 h2 = *(const float4*)&hs[(half * 4 + 2) * 128 + k];
      float4 h3 = *(const float4*)&hs[(half * 4 + 3) * 128 + k];
      acc0 += h0.x * w.x + h0.y * w.y + h0.z * w.z + h0.w * w.w;
      acc1 += h1.x * w.x + h1.y * w.y + h1.z * w.z + h1.w * w.w;
      acc2 += h2.x * w.x + h2.y * w.y + h2.z * w.z + h2.w * w.w;
      acc3 += h3.x * w.x + h3.y * w.y + h3.z * w.z + h3.w * w.w;
    }
    int r0 = base + half * 4;
    out[(size_t)(r0 + 0) * DIM + col] = acc0;
    out[(size_t)(r0 + 1) * DIM + col] = acc1;
    out[(size_t)(r0 + 2) * DIM + col] = acc2;
    out[(size_t)(r0 + 3) * DIM + col] = acc3;
  }
}

// out[i][d] = maybe_relu( dinv[i]*sum_j dinv[src_j]*xw[src_j][d] + dinv[i]^2*xw[i][d] + b[d] )
__global__ __launch_bounds__(128) void agg_kernel(const float* __restrict__ xw,
                                                  const int* __restrict__ offs,
                                                  const int* __restrict__ csr_src,
                                                  const float* __restrict__ dinv,
                                                  const float* __restrict__ bias,
                                                  float* __restrict__ out, int relu) {
  int i = blockIdx.x;
  int d = threadIdx.x;
  int s0 = offs[i], s1 = offs[i + 1];
  float acc = 0.f;
  for (int j = s0; j < s1; ++j) {
    int s = csr_src[j];
    acc += dinv[s] * xw[(size_t)s * DIM + d];
  }
  float di = dinv[i];
  float v = di * acc + di * di * xw[(size_t)i * DIM + d] + bias[d];
  if (relu) v = fmaxf(v, 0.f);
  out[(size_t)i * DIM + d] = v;
}

// batch is sorted: per-block run-length accumulation, few atomics
__global__ __launch_bounds__(128) void readout_kernel(const float* __restrict__ h,
                                                      const int* __restrict__ batch,
                                                      unsigned* __restrict__ gmaxk,
                                                      float* __restrict__ gsum) {
  int d = threadIdx.x;
  int start = blockIdx.x * 256;
  if (start >= NNODES) return;
  int end = min(start + 256, NNODES);
  int cur = batch[start];
  float s = 0.f, m = -INFINITY;
  for (int i = start; i < end; ++i) {
    int g = batch[i];
    float v = h[(size_t)i * DIM + d];
    if (g != cur) {
      atomicAdd(&gsum[cur * DIM + d], s);
      atomicMax(&gmaxk[cur * DIM + d], fkey(m));
      cur = g; s = 0.f; m = -INFINITY;
    }
    s += v;
    m = fmaxf(m, v);
  }
  atomicAdd(&gsum[cur * DIM + d], s);
  atomicMax(&gmaxk[cur * DIM + d], fkey(m));
}

__global__ void pack_kernel(const unsigned* __restrict__ gmaxk,
                            const float* __restrict__ gsum, float* __restrict__ out) {
  int idx = blockIdx.x * blockDim.x + threadIdx.x;
  if (idx >= NGRAPHS * 256) return;
  int g = idx >> 8, d = idx & 255;
  float v = (d < 128) ? fdecode(gmaxk[g * DIM + d]) : gsum[g * DIM + (d - 128)];
  out[idx] = rintf(v * 1000.0f) / 1000.0f;
}

extern "C" void kernel_launch(void* const* d_in, const int* in_sizes, int n_in,
                              void* d_out, int out_size, void* d_ws, size_t ws_size,
                              hipStream_t stream) {
  const int* node_type = (const int*)d_in[0];
  const int* ninv      = (const int*)d_in[1];
  const int* edge      = (const int*)d_in[2];
  const int* batch     = (const int*)d_in[3];
  const float* emb_type = (const float*)d_in[4];
  const float* emb_inv  = (const float*)d_in[5];
  const float* W[3] = {(const float*)d_in[6], (const float*)d_in[8], (const float*)d_in[10]};
  const float* B[3] = {(const float*)d_in[7], (const float*)d_in[9], (const float*)d_in[11]};
  const int* srcp = edge;
  const int* dstp = edge + NEDGES;
  float* out = (float*)d_out;

  char* ws = (char*)d_ws;
  auto alloc = [&](size_t bytes) {
    char* p = ws;
    ws += (bytes + 255) & ~(size_t)255;
    return p;
  };
  float* hA      = (float*)alloc((size_t)NNODES * DIM * 4);
  float* hB      = (float*)alloc((size_t)NNODES * DIM * 4);
  int* cnt       = (int*)alloc((size_t)NNODES * 4);
  float* dinv    = (float*)alloc((size_t)NNODES * 4);
  int* offs      = (int*)alloc((size_t)(NNODES + 1) * 4);
  int* cursor    = (int*)alloc((size_t)NNODES * 4);
  int* csr_src   = (int*)alloc((size_t)NEDGES * 4);
  unsigned* gmaxk = (unsigned*)alloc((size_t)NGRAPHS * DIM * 4);
  float* gsum    = (float*)alloc((size_t)NGRAPHS * DIM * 4);

  hipMemsetAsync(cnt, 0, (size_t)NNODES * 4, stream);
  hipMemsetAsync(gmaxk, 0, (size_t)NGRAPHS * DIM * 4, stream);
  hipMemsetAsync(gsum, 0, (size_t)NGRAPHS * DIM * 4, stream);

  count_kernel<<<(NEDGES + 255) / 256, 256, 0, stream>>>(dstp, cnt);
  dinv_kernel<<<(NNODES + 255) / 256, 256, 0, stream>>>(cnt, dinv);
  scan_kernel<<<1, 1024, 0, stream>>>(cnt, offs, cursor);
  fill_kernel<<<(NEDGES + 255) / 256, 256, 0, stream>>>(srcp, dstp, cursor, csr_src);
  encoder_kernel<<<(NNODES * DIM + 255) / 256, 256, 0, stream>>>(node_type, ninv, emb_type, emb_inv, hA);

  for (int l = 0; l < 3; ++l) {
    gemm_kernel<<<2048, 256, 0, stream>>>(hA, W[l], hB, NNODES);
    agg_kernel<<<NNODES, 128, 0, stream>>>(hB, offs, csr_src, dinv, B[l], hA, l < 2 ? 1 : 0);
  }

  readout_kernel<<<(NNODES + 255) / 256, 128, 0, stream>>>(hA, batch, gmaxk, gsum);
  pack_kernel<<<64, 256, 0, stream>>>(gmaxk, gsum, out);
}

// Round 2
// 810.831 us; speedup vs baseline: 1.6053x; 1.6053x over previous
//
#include <hip/hip_runtime.h>
#include <hip/hip_bf16.h>
#include <cstdint>

#define NNODES 100000
#define NEDGES 1600000
#define NGRAPHS 64
#define DIM 128
#define SCAN_NBLK ((NNODES + 255) / 256)   // 391

typedef __attribute__((ext_vector_type(8))) short bf16x8;
typedef __attribute__((ext_vector_type(4))) float f32x4;

__device__ inline ushort f2bf(float f) {
  __hip_bfloat16 h = __float2bfloat16(f);
  return __builtin_bit_cast(ushort, h);
}
__device__ inline float bf2f(ushort u) {
  return __uint_as_float(((unsigned)u) << 16);
}
__device__ inline unsigned fkey(float f) {
  unsigned b = __float_as_uint(f);
  return (b & 0x80000000u) ? ~b : (b | 0x80000000u);
}
__device__ inline float fdecode(unsigned k) {
  unsigned b = (k & 0x80000000u) ? (k & 0x7FFFFFFFu) : ~k;
  return __uint_as_float(b);
}

// ---------------- preprocessing ----------------

__global__ void count_kernel(const int* __restrict__ dst, int* __restrict__ cnt) {
  int e = blockIdx.x * blockDim.x + threadIdx.x;
  if (e < NEDGES) atomicAdd(&cnt[dst[e]], 1);
}

__global__ __launch_bounds__(256) void scan_bsum(const int* __restrict__ cnt,
                                                 int* __restrict__ bsum) {
  __shared__ int sdata[4];
  int i = blockIdx.x * 256 + threadIdx.x;
  int v = (i < NNODES) ? cnt[i] : 0;
  for (int o = 32; o; o >>= 1) v += __shfl_down(v, o);
  if ((threadIdx.x & 63) == 0) sdata[threadIdx.x >> 6] = v;
  __syncthreads();
  if (threadIdx.x == 0) bsum[blockIdx.x] = sdata[0] + sdata[1] + sdata[2] + sdata[3];
}

__global__ __launch_bounds__(512) void scan_bpre(const int* __restrict__ bsum,
                                                 int* __restrict__ bpre) {
  __shared__ int buf[512];
  int tid = threadIdx.x;
  int v = (tid < SCAN_NBLK) ? bsum[tid] : 0;
  buf[tid] = v;
  __syncthreads();
  for (int o = 1; o < 512; o <<= 1) {
    int t = (tid >= o) ? buf[tid - o] : 0;
    __syncthreads();
    buf[tid] += t;
    __syncthreads();
  }
  if (tid < SCAN_NBLK) bpre[tid] = buf[tid] - v;
}

__global__ __launch_bounds__(256) void scan_apply(const int* __restrict__ cnt,
                                                  const int* __restrict__ bpre,
                                                  int* __restrict__ offs,
                                                  int* __restrict__ cursor,
                                                  float* __restrict__ dinv) {
  __shared__ int buf[256];
  int tid = threadIdx.x;
  int i = blockIdx.x * 256 + tid;
  int v = (i < NNODES) ? cnt[i] : 0;
  buf[tid] = v;
  __syncthreads();
  for (int o = 1; o < 256; o <<= 1) {
    int t = (tid >= o) ? buf[tid - o] : 0;
    __syncthreads();
    buf[tid] += t;
    __syncthreads();
  }
  int excl = bpre[blockIdx.x] + buf[tid] - v;
  if (i < NNODES) {
    offs[i] = excl;
    cursor[i] = excl;
    dinv[i] = rsqrtf((float)v + 1.0f);
  }
  if (i == 0) offs[NNODES] = NEDGES;
}

__global__ void fill_kernel(const int* __restrict__ src, const int* __restrict__ dst,
                            int* __restrict__ cursor, int* __restrict__ csr_src) {
  int e = blockIdx.x * blockDim.x + threadIdx.x;
  if (e < NEDGES) {
    int pos = atomicAdd(&cursor[dst[e]], 1);
    csr_src[pos] = src[e];
  }
}

// ---------------- encoder (writes bf16 h) ----------------

__global__ void encoder_kernel(const int* __restrict__ nt, const int* __restrict__ ninv,
                               const float* __restrict__ et, const float* __restrict__ ei,
                               ushort* __restrict__ h) {
  int idx = blockIdx.x * blockDim.x + threadIdx.x;
  if (idx >= NNODES * 32) return;
  int i = idx >> 5, d4 = (idx & 31) << 2;
  float4 a = *(const float4*)(et + nt[i] * DIM + d4);
  float4 b = *(const float4*)(ei + ninv[i] * DIM + d4);
  uint2 o;
  o.x = ((unsigned)f2bf(a.y + b.y) << 16) | f2bf(a.x + b.x);
  o.y = ((unsigned)f2bf(a.w + b.w) << 16) | f2bf(a.z + b.z);
  *(uint2*)(h + (size_t)i * DIM + d4) = o;
}

__global__ void wcvt_kernel(const float* __restrict__ w, ushort* __restrict__ o) {
  int idx = blockIdx.x * blockDim.x + threadIdx.x;
  if (idx < DIM * DIM) o[idx] = f2bf(w[idx]);
}

// ---------------- MFMA GEMM: xw = h @ W  (bf16 in, bf16 out, f32 accum) ----------------
// per block: 4 waves x 16 rows = 64 rows, N=128 (8 n-tiles), K=128 (4 k-steps of 32)

__global__ __launch_bounds__(256) void gemm_kernel(const ushort* __restrict__ h,
                                                   const ushort* __restrict__ wb,
                                                   ushort* __restrict__ out) {
  // Ws pre-swizzled into B-fragment order: [(ks*8+t)*64 + lane] * 8 + j
  __shared__ ushort Ws[32 * 64 * 8];  // 32 KiB
  int tid = threadIdx.x;
  for (int g = tid; g < 2048; g += 256) {
    int kt = g >> 6, l = g & 63;
    int ks = kt >> 3, t = kt & 7;
    int kb = ks * 32 + ((l >> 4) << 3);
    int col = t * 16 + (l & 15);
#pragma unroll
    for (int j = 0; j < 8; ++j) Ws[g * 8 + j] = wb[(kb + j) * DIM + col];
  }
  __syncthreads();
  int w = tid >> 6, lane = tid & 63;
  int row0 = (blockIdx.x * 4 + w) * 16;
  if (row0 >= NNODES) return;
  const ushort* hrow = h + (size_t)(row0 + (lane & 15)) * DIM + ((lane >> 4) << 3);
  f32x4 acc[8];
#pragma unroll
  for (int t = 0; t < 8; ++t) acc[t] = {0.f, 0.f, 0.f, 0.f};
#pragma unroll
  for (int ks = 0; ks < 4; ++ks) {
    bf16x8 a = *(const bf16x8*)(hrow + ks * 32);
#pragma unroll
    for (int t = 0; t < 8; ++t) {
      bf16x8 b = *(const bf16x8*)&Ws[((ks * 8 + t) * 64 + lane) * 8];
      acc[t] = __builtin_amdgcn_mfma_f32_16x16x32_bf16(a, b, acc[t], 0, 0, 0);
    }
  }
  int rbase = row0 + ((lane >> 4) << 2);
  int cbase = lane & 15;
#pragma unroll
  for (int t = 0; t < 8; ++t)
#pragma unroll
    for (int r = 0; r < 4; ++r)
      out[(size_t)(rbase + r) * DIM + t * 16 + cbase] = f2bf(acc[t][r]);
}

// ---------------- aggregation: one wave per node, bf16 gather ----------------

__global__ __launch_bounds__(256) void agg_kernel(const ushort* __restrict__ xw,
                                                  const int* __restrict__ offs,
                                                  const int* __restrict__ csr_src,
                                                  const float* __restrict__ dinv,
                                                  const float* __restrict__ bias,
                                                  ushort* __restrict__ outb,
                                                  float* __restrict__ outf, int relu) {
  int i = blockIdx.x * 4 + (threadIdx.x >> 6);
  if (i >= NNODES) return;
  int lane = threadIdx.x & 63;
  int s0 = offs[i], s1 = offs[i + 1];
  float ax = 0.f, ay = 0.f;
  for (int j = s0; j < s1; ++j) {
    int s = csr_src[j];
    float ds = dinv[s];
    unsigned pv = *(const unsigned*)(xw + (size_t)s * DIM + lane * 2);
    ax += ds * bf2f((ushort)(pv & 0xffffu));
    ay += ds * bf2f((ushort)(pv >> 16));
  }
  float di = dinv[i];
  unsigned ps = *(const unsigned*)(xw + (size_t)i * DIM + lane * 2);
  float2 b = *(const float2*)(bias + lane * 2);
  float vx = di * ax + di * di * bf2f((ushort)(ps & 0xffffu)) + b.x;
  float vy = di * ay + di * di * bf2f((ushort)(ps >> 16)) + b.y;
  if (relu) { vx = fmaxf(vx, 0.f); vy = fmaxf(vy, 0.f); }
  if (outf) {
    *(float2*)(outf + (size_t)i * DIM + lane * 2) = make_float2(vx, vy);
  } else {
    *(unsigned*)(outb + (size_t)i * DIM + lane * 2) =
        ((unsigned)f2bf(vy) << 16) | f2bf(vx);
  }
}

// ---------------- readout ----------------

__global__ __launch_bounds__(128) void readout_kernel(const float* __restrict__ h,
                                                      const int* __restrict__ batch,
                                                      unsigned* __restrict__ gmaxk,
                                                      float* __restrict__ gsum) {
  int d = threadIdx.x;
  int start = blockIdx.x * 256;
  if (start >= NNODES) return;
  int end = min(start + 256, NNODES);
  int cur = batch[start];
  float s = 0.f, m = -INFINITY;
  for (int i = start; i < end; ++i) {
    int g = batch[i];
    float v = h[(size_t)i * DIM + d];
    if (g != cur) {
      atomicAdd(&gsum[cur * DIM + d], s);
      atomicMax(&gmaxk[cur * DIM + d], fkey(m));
      cur = g; s = 0.f; m = -INFINITY;
    }
    s += v;
    m = fmaxf(m, v);
  }
  atomicAdd(&gsum[cur * DIM + d], s);
  atomicMax(&gmaxk[cur * DIM + d], fkey(m));
}

__global__ void pack_kernel(const unsigned* __restrict__ gmaxk,
                            const float* __restrict__ gsum, float* __restrict__ out) {
  int idx = blockIdx.x * blockDim.x + threadIdx.x;
  if (idx >= NGRAPHS * 256) return;
  int g = idx >> 8, d = idx & 255;
  float v = (d < 128) ? fdecode(gmaxk[g * DIM + d]) : gsum[g * DIM + (d - 128)];
  out[idx] = rintf(v * 1000.0f) / 1000.0f;
}

// ---------------- launch ----------------

extern "C" void kernel_launch(void* const* d_in, const int* in_sizes, int n_in,
                              void* d_out, int out_size, void* d_ws, size_t ws_size,
                              hipStream_t stream) {
  const int* node_type = (const int*)d_in[0];
  const int* ninv      = (const int*)d_in[1];
  const int* edge      = (const int*)d_in[2];
  const int* batch     = (const int*)d_in[3];
  const float* emb_type = (const float*)d_in[4];
  const float* emb_inv  = (const float*)d_in[5];
  const float* W[3] = {(const float*)d_in[6], (const float*)d_in[8], (const float*)d_in[10]};
  const float* B[3] = {(const float*)d_in[7], (const float*)d_in[9], (const float*)d_in[11]};
  const int* srcp = edge;
  const int* dstp = edge + NEDGES;
  float* out = (float*)d_out;

  char* ws = (char*)d_ws;
  auto alloc = [&](size_t bytes) {
    char* p = ws;
    ws += (bytes + 255) & ~(size_t)255;
    return p;
  };
  ushort* hA     = (ushort*)alloc((size_t)NNODES * DIM * 2);
  ushort* xw     = (ushort*)alloc((size_t)NNODES * DIM * 2);
  float* h2f     = (float*)alloc((size_t)NNODES * DIM * 4);
  int* cnt       = (int*)alloc((size_t)NNODES * 4);
  float* dinv    = (float*)alloc((size_t)NNODES * 4);
  int* offs      = (int*)alloc((size_t)(NNODES + 1) * 4);
  int* cursor    = (int*)alloc((size_t)NNODES * 4);
  int* csr_src   = (int*)alloc((size_t)NEDGES * 4);
  int* bsum      = (int*)alloc((size_t)SCAN_NBLK * 4);
  int* bpre      = (int*)alloc((size_t)SCAN_NBLK * 4);
  ushort* wbf    = (ushort*)alloc((size_t)3 * DIM * DIM * 2);
  unsigned* gmaxk = (unsigned*)alloc((size_t)NGRAPHS * DIM * 4);
  float* gsum    = (float*)alloc((size_t)NGRAPHS * DIM * 4);

  hipMemsetAsync(cnt, 0, (size_t)NNODES * 4, stream);
  hipMemsetAsync(gmaxk, 0, (size_t)NGRAPHS * DIM * 4, stream);
  hipMemsetAsync(gsum, 0, (size_t)NGRAPHS * DIM * 4, stream);

  count_kernel<<<NEDGES / 256, 256, 0, stream>>>(dstp, cnt);
  scan_bsum<<<SCAN_NBLK, 256, 0, stream>>>(cnt, bsum);
  scan_bpre<<<1, 512, 0, stream>>>(bsum, bpre);
  scan_apply<<<SCAN_NBLK, 256, 0, stream>>>(cnt, bpre, offs, cursor, dinv);
  fill_kernel<<<NEDGES / 256, 256, 0, stream>>>(srcp, dstp, cursor, csr_src);

  for (int l = 0; l < 3; ++l)
    wcvt_kernel<<<64, 256, 0, stream>>>(W[l], wbf + (size_t)l * DIM * DIM);
  encoder_kernel<<<NNODES * 32 / 256, 256, 0, stream>>>(node_type, ninv, emb_type, emb_inv, hA);

  for (int l = 0; l < 3; ++l) {
    gemm_kernel<<<(NNODES / 16 + 3) / 4, 256, 0, stream>>>(hA, wbf + (size_t)l * DIM * DIM, xw);
    agg_kernel<<<NNODES / 4, 256, 0, stream>>>(xw, offs, csr_src, dinv, B[l],
                                               hA, (l == 2) ? h2f : nullptr, l < 2 ? 1 : 0);
  }

  readout_kernel<<<SCAN_NBLK, 128, 0, stream>>>(h2f, batch, gmaxk, gsum);
  pack_kernel<<<64, 256, 0, stream>>>(gmaxk, gsum, out);
}

// Round 3
// 509.675 us; speedup vs baseline: 2.5539x; 1.5909x over previous
//
#include <hip/hip_runtime.h>
#include <hip/hip_bf16.h>
#include <cstdint>

#define NNODES 100000
#define NEDGES 1600000
#define NGRAPHS 64
#define DIM 128
#define SCAN_NBLK ((NNODES + 255) / 256)   // 391

typedef __attribute__((ext_vector_type(8))) short bf16x8;
typedef __attribute__((ext_vector_type(4))) float f32x4;

__device__ inline ushort f2bf(float f) {
  __hip_bfloat16 h = __float2bfloat16(f);
  return __builtin_bit_cast(ushort, h);
}
__device__ inline float bf2f(ushort u) {
  return __uint_as_float(((unsigned)u) << 16);
}
__device__ inline unsigned fkey(float f) {
  unsigned b = __float_as_uint(f);
  return (b & 0x80000000u) ? ~b : (b | 0x80000000u);
}
__device__ inline float fdecode(unsigned k) {
  unsigned b = (k & 0x80000000u) ? (k & 0x7FFFFFFFu) : ~k;
  return __uint_as_float(b);
}

// ---------------- preprocessing ----------------

__global__ void count_kernel(const int* __restrict__ dst, int* __restrict__ cnt) {
  int e = blockIdx.x * blockDim.x + threadIdx.x;
  if (e < NEDGES) atomicAdd(&cnt[dst[e]], 1);
}

__global__ __launch_bounds__(256) void scan_bsum(const int* __restrict__ cnt,
                                                 int* __restrict__ bsum) {
  __shared__ int sdata[4];
  int i = blockIdx.x * 256 + threadIdx.x;
  int v = (i < NNODES) ? cnt[i] : 0;
  for (int o = 32; o; o >>= 1) v += __shfl_down(v, o);
  if ((threadIdx.x & 63) == 0) sdata[threadIdx.x >> 6] = v;
  __syncthreads();
  if (threadIdx.x == 0) bsum[blockIdx.x] = sdata[0] + sdata[1] + sdata[2] + sdata[3];
}

__global__ __launch_bounds__(512) void scan_bpre(const int* __restrict__ bsum,
                                                 int* __restrict__ bpre) {
  __shared__ int buf[512];
  int tid = threadIdx.x;
  int v = (tid < SCAN_NBLK) ? bsum[tid] : 0;
  buf[tid] = v;
  __syncthreads();
  for (int o = 1; o < 512; o <<= 1) {
    int t = (tid >= o) ? buf[tid - o] : 0;
    __syncthreads();
    buf[tid] += t;
    __syncthreads();
  }
  if (tid < SCAN_NBLK) bpre[tid] = buf[tid] - v;
}

__global__ __launch_bounds__(256) void scan_apply(const int* __restrict__ cnt,
                                                  const int* __restrict__ bpre,
                                                  int* __restrict__ offs,
                                                  int* __restrict__ cursor,
                                                  float* __restrict__ dinv) {
  __shared__ int buf[256];
  int tid = threadIdx.x;
  int i = blockIdx.x * 256 + tid;
  int v = (i < NNODES) ? cnt[i] : 0;
  buf[tid] = v;
  __syncthreads();
  for (int o = 1; o < 256; o <<= 1) {
    int t = (tid >= o) ? buf[tid - o] : 0;
    __syncthreads();
    buf[tid] += t;
    __syncthreads();
  }
  int excl = bpre[blockIdx.x] + buf[tid] - v;
  if (i < NNODES) {
    offs[i] = excl;
    cursor[i] = excl;
    dinv[i] = rsqrtf((float)v + 1.0f);
  }
  if (i == 0) offs[NNODES] = NEDGES;
}

__global__ void fill_kernel(const int* __restrict__ src, const int* __restrict__ dst,
                            int* __restrict__ cursor, int* __restrict__ csr_src) {
  int e = blockIdx.x * blockDim.x + threadIdx.x;
  if (e < NEDGES) {
    int pos = atomicAdd(&cursor[dst[e]], 1);
    csr_src[pos] = src[e];
  }
}

// ---------------- encoder (writes bf16 h) ----------------

__global__ void encoder_kernel(const int* __restrict__ nt, const int* __restrict__ ninv,
                               const float* __restrict__ et, const float* __restrict__ ei,
                               ushort* __restrict__ h) {
  int idx = blockIdx.x * blockDim.x + threadIdx.x;
  if (idx >= NNODES * 32) return;
  int i = idx >> 5, d4 = (idx & 31) << 2;
  float4 a = *(const float4*)(et + nt[i] * DIM + d4);
  float4 b = *(const float4*)(ei + ninv[i] * DIM + d4);
  uint2 o;
  o.x = ((unsigned)f2bf(a.y + b.y) << 16) | f2bf(a.x + b.x);
  o.y = ((unsigned)f2bf(a.w + b.w) << 16) | f2bf(a.z + b.z);
  *(uint2*)(h + (size_t)i * DIM + d4) = o;
}

__global__ void wcvt_kernel(const float* __restrict__ w, ushort* __restrict__ o) {
  int idx = blockIdx.x * blockDim.x + threadIdx.x;
  if (idx < 3 * DIM * DIM) o[idx] = f2bf(w[idx]);
}

// ---------------- MFMA GEMM: xws = dinv * (h @ W)  (bf16 in/out, f32 accum) ----------------
// persistent: 4 waves/block, each wave computes 16-row tiles, grid-stride over 6250 tiles

__global__ __launch_bounds__(256) void gemm_kernel(const ushort* __restrict__ h,
                                                   const ushort* __restrict__ wb,
                                                   const float* __restrict__ dinv,
                                                   ushort* __restrict__ out) {
  // Ws pre-swizzled into B-fragment order: [(ks*8+t)*64 + lane] * 8 + j
  __shared__ ushort Ws[32 * 64 * 8];  // 32 KiB
  int tid = threadIdx.x;
  for (int g = tid; g < 2048; g += 256) {
    int kt = g >> 6, l = g & 63;
    int ks = kt >> 3, t = kt & 7;
    int kb = ks * 32 + ((l >> 4) << 3);
    int col = t * 16 + (l & 15);
#pragma unroll
    for (int j = 0; j < 8; ++j) Ws[g * 8 + j] = wb[(kb + j) * DIM + col];
  }
  __syncthreads();
  int w = tid >> 6, lane = tid & 63;
  for (int tile = blockIdx.x * 4 + w; tile < NNODES / 16; tile += gridDim.x * 4) {
    int row0 = tile * 16;
    const ushort* hrow = h + (size_t)(row0 + (lane & 15)) * DIM + ((lane >> 4) << 3);
    f32x4 acc[8];
#pragma unroll
    for (int t = 0; t < 8; ++t) acc[t] = {0.f, 0.f, 0.f, 0.f};
#pragma unroll
    for (int ks = 0; ks < 4; ++ks) {
      bf16x8 a = *(const bf16x8*)(hrow + ks * 32);
#pragma unroll
      for (int t = 0; t < 8; ++t) {
        bf16x8 b = *(const bf16x8*)&Ws[((ks * 8 + t) * 64 + lane) * 8];
        acc[t] = __builtin_amdgcn_mfma_f32_16x16x32_bf16(a, b, acc[t], 0, 0, 0);
      }
    }
    int rbase = row0 + ((lane >> 4) << 2);
    int cbase = lane & 15;
    float4 dv = *(const float4*)(dinv + rbase);
    float dvr[4] = {dv.x, dv.y, dv.z, dv.w};
#pragma unroll
    for (int t = 0; t < 8; ++t)
#pragma unroll
      for (int r = 0; r < 4; ++r)
        out[(size_t)(rbase + r) * DIM + t * 16 + cbase] = f2bf(acc[t][r] * dvr[r]);
  }
}

// ---------------- aggregation: one wave per node, 8-deep MLP gather ----------------
// out[i] = dinv[i] * (sum_j xws[src_j] + xws[i]) + b

__global__ __launch_bounds__(256) void agg_kernel(const ushort* __restrict__ xws,
                                                  const int* __restrict__ offs,
                                                  const int* __restrict__ csr_src,
                                                  const float* __restrict__ dinv,
                                                  const float* __restrict__ bias,
                                                  ushort* __restrict__ outb,
                                                  float* __restrict__ outf, int relu) {
  int i = blockIdx.x * 4 + (threadIdx.x >> 6);
  if (i >= NNODES) return;
  int lane = threadIdx.x & 63;
  int s0 = offs[i], s1 = offs[i + 1];
  float ax = 0.f, ay = 0.f;
  int j = s0;
  for (; j + 8 <= s1; j += 8) {
    int s[8];
#pragma unroll
    for (int u = 0; u < 8; ++u) s[u] = csr_src[j + u];
    unsigned p[8];
#pragma unroll
    for (int u = 0; u < 8; ++u)
      p[u] = *(const unsigned*)(xws + (size_t)s[u] * DIM + lane * 2);
#pragma unroll
    for (int u = 0; u < 8; ++u) {
      ax += bf2f((ushort)(p[u] & 0xffffu));
      ay += bf2f((ushort)(p[u] >> 16));
    }
  }
  for (; j + 2 <= s1; j += 2) {
    int sa = csr_src[j], sb = csr_src[j + 1];
    unsigned pa = *(const unsigned*)(xws + (size_t)sa * DIM + lane * 2);
    unsigned pb = *(const unsigned*)(xws + (size_t)sb * DIM + lane * 2);
    ax += bf2f((ushort)(pa & 0xffffu)) + bf2f((ushort)(pb & 0xffffu));
    ay += bf2f((ushort)(pa >> 16)) + bf2f((ushort)(pb >> 16));
  }
  if (j < s1) {
    int sa = csr_src[j];
    unsigned pa = *(const unsigned*)(xws + (size_t)sa * DIM + lane * 2);
    ax += bf2f((ushort)(pa & 0xffffu));
    ay += bf2f((ushort)(pa >> 16));
  }
  unsigned ps = *(const unsigned*)(xws + (size_t)i * DIM + lane * 2);
  ax += bf2f((ushort)(ps & 0xffffu));
  ay += bf2f((ushort)(ps >> 16));
  float di = dinv[i];
  float2 b = *(const float2*)(bias + lane * 2);
  float vx = di * ax + b.x;
  float vy = di * ay + b.y;
  if (relu) { vx = fmaxf(vx, 0.f); vy = fmaxf(vy, 0.f); }
  if (outf) {
    *(float2*)(outf + (size_t)i * DIM + lane * 2) = make_float2(vx, vy);
  } else {
    *(unsigned*)(outb + (size_t)i * DIM + lane * 2) =
        ((unsigned)f2bf(vy) << 16) | f2bf(vx);
  }
}

// ---------------- readout ----------------

__global__ __launch_bounds__(128) void readout_kernel(const float* __restrict__ h,
                                                      const int* __restrict__ batch,
                                                      unsigned* __restrict__ gmaxk,
                                                      float* __restrict__ gsum) {
  int d = threadIdx.x;
  int start = blockIdx.x * 128;
  if (start >= NNODES) return;
  int end = min(start + 128, NNODES);
  int cur = batch[start];
  float s = 0.f, m = -INFINITY;
  for (int i = start; i < end; ++i) {
    int g = batch[i];
    float v = h[(size_t)i * DIM + d];
    if (g != cur) {
      atomicAdd(&gsum[cur * DIM + d], s);
      atomicMax(&gmaxk[cur * DIM + d], fkey(m));
      cur = g; s = 0.f; m = -INFINITY;
    }
    s += v;
    m = fmaxf(m, v);
  }
  atomicAdd(&gsum[cur * DIM + d], s);
  atomicMax(&gmaxk[cur * DIM + d], fkey(m));
}

__global__ void pack_kernel(const unsigned* __restrict__ gmaxk,
                            const float* __restrict__ gsum, float* __restrict__ out) {
  int idx = blockIdx.x * blockDim.x + threadIdx.x;
  if (idx >= NGRAPHS * 256) return;
  int g = idx >> 8, d = idx & 255;
  float v = (d < 128) ? fdecode(gmaxk[g * DIM + d]) : gsum[g * DIM + (d - 128)];
  out[idx] = rintf(v * 1000.0f) / 1000.0f;
}

// ---------------- launch ----------------

extern "C" void kernel_launch(void* const* d_in, const int* in_sizes, int n_in,
                              void* d_out, int out_size, void* d_ws, size_t ws_size,
                              hipStream_t stream) {
  const int* node_type = (const int*)d_in[0];
  const int* ninv      = (const int*)d_in[1];
  const int* edge      = (const int*)d_in[2];
  const int* batch     = (const int*)d_in[3];
  const float* emb_type = (const float*)d_in[4];
  const float* emb_inv  = (const float*)d_in[5];
  const float* B[3] = {(const float*)d_in[7], (const float*)d_in[9], (const float*)d_in[11]};
  const int* srcp = edge;
  const int* dstp = edge + NEDGES;
  float* out = (float*)d_out;

  char* ws = (char*)d_ws;
  auto alloc = [&](size_t bytes) {
    char* p = ws;
    ws += (bytes + 255) & ~(size_t)255;
    return p;
  };
  ushort* hA     = (ushort*)alloc((size_t)NNODES * DIM * 2);
  ushort* xws    = (ushort*)alloc((size_t)NNODES * DIM * 2);
  float* h2f     = (float*)alloc((size_t)NNODES * DIM * 4);
  int* cnt       = (int*)alloc((size_t)NNODES * 4);
  float* dinv    = (float*)alloc((size_t)NNODES * 4);
  int* offs      = (int*)alloc((size_t)(NNODES + 1) * 4);
  int* cursor    = (int*)alloc((size_t)NNODES * 4);
  int* csr_src   = (int*)alloc((size_t)NEDGES * 4);
  int* bsum      = (int*)alloc((size_t)SCAN_NBLK * 4);
  int* bpre      = (int*)alloc((size_t)SCAN_NBLK * 4);
  ushort* wbf    = (ushort*)alloc((size_t)3 * DIM * DIM * 2);
  unsigned* gmaxk = (unsigned*)alloc((size_t)NGRAPHS * DIM * 4);
  float* gsum    = (float*)alloc((size_t)NGRAPHS * DIM * 4);

  hipMemsetAsync(cnt, 0, (size_t)NNODES * 4, stream);
  hipMemsetAsync(gmaxk, 0, (size_t)NGRAPHS * DIM * 4, stream);
  hipMemsetAsync(gsum, 0, (size_t)NGRAPHS * DIM * 4, stream);

  count_kernel<<<NEDGES / 256, 256, 0, stream>>>(dstp, cnt);
  scan_bsum<<<SCAN_NBLK, 256, 0, stream>>>(cnt, bsum);
  scan_bpre<<<1, 512, 0, stream>>>(bsum, bpre);
  scan_apply<<<SCAN_NBLK, 256, 0, stream>>>(cnt, bpre, offs, cursor, dinv);
  fill_kernel<<<NEDGES / 256, 256, 0, stream>>>(srcp, dstp, cursor, csr_src);

  {
    const float* wcat[3] = {(const float*)d_in[6], (const float*)d_in[8], (const float*)d_in[10]};
    for (int l = 0; l < 3; ++l)
      wcvt_kernel<<<64, 256, 0, stream>>>(wcat[l] - (size_t)0, wbf + (size_t)l * DIM * DIM);
  }
  encoder_kernel<<<NNODES * 32 / 256, 256, 0, stream>>>(node_type, ninv, emb_type, emb_inv, hA);

  for (int l = 0; l < 3; ++l) {
    gemm_kernel<<<256, 256, 0, stream>>>(hA, wbf + (size_t)l * DIM * DIM, dinv, xws);
    agg_kernel<<<NNODES / 4, 256, 0, stream>>>(xws, offs, csr_src, dinv, B[l],
                                               hA, (l == 2) ? h2f : nullptr, l < 2 ? 1 : 0);
  }

  readout_kernel<<<(NNODES + 127) / 128, 128, 0, stream>>>(h2f, batch, gmaxk, gsum);
  pack_kernel<<<64, 256, 0, stream>>>(gmaxk, gsum, out);
}

// Round 4
// 401.307 us; speedup vs baseline: 3.2435x; 1.2700x over previous
//
#include <hip/hip_runtime.h>
#include <hip/hip_bf16.h>
#include <cstdint>

#define NNODES 100000
#define NEDGES 1600000
#define NGRAPHS 64
#define DIM 128

#define NB 196          // buckets: dst >> 9 (512 nodes each)
#define BSHIFT 9
#define STAGE_CAP 32
#define FLUSH_THRESH 24
#define MS_BLOCKS 256
#define MS_EPB (NEDGES / MS_BLOCKS)       // 6250
#define MS_ROUNDS ((MS_EPB + 255) / 256)  // 25
#define BH_BLOCKS 200
#define BH_EPB (NEDGES / BH_BLOCKS)       // 8000
#define EB_CAP 10000                       // max edges per bucket (mean 8163, 20 sigma)

typedef __attribute__((ext_vector_type(8))) short bf16x8;
typedef __attribute__((ext_vector_type(4))) float f32x4;

__device__ inline ushort f2bf(float f) {
  __hip_bfloat16 h = __float2bfloat16(f);
  return __builtin_bit_cast(ushort, h);
}
__device__ inline float bf2f(ushort u) {
  return __uint_as_float(((unsigned)u) << 16);
}
__device__ inline unsigned fkey(float f) {
  unsigned b = __float_as_uint(f);
  return (b & 0x80000000u) ? ~b : (b | 0x80000000u);
}
__device__ inline float fdecode(unsigned k) {
  unsigned b = (k & 0x80000000u) ? (k & 0x7FFFFFFFu) : ~k;
  return __uint_as_float(b);
}

// ---------------- preprocessing: bucketed counting sort ----------------

__global__ __launch_bounds__(256) void bucket_hist(const int* __restrict__ dst,
                                                   int* __restrict__ bhist) {
  __shared__ int bh[NB];
  int tid = threadIdx.x;
  if (tid < NB) bh[tid] = 0;
  __syncthreads();
  int base = blockIdx.x * BH_EPB;
  for (int k = base + tid; k < base + BH_EPB; k += 256)
    atomicAdd(&bh[dst[k] >> BSHIFT], 1);
  __syncthreads();
  if (tid < NB && bh[tid]) atomicAdd(&bhist[tid], bh[tid]);
}

__global__ __launch_bounds__(256) void bucket_scan(const int* __restrict__ bhist,
                                                   int* __restrict__ bbase,
                                                   int* __restrict__ gcur,
                                                   int* __restrict__ offs) {
  __shared__ int buf[256];
  int tid = threadIdx.x;
  int v = (tid < NB) ? bhist[tid] : 0;
  buf[tid] = v;
  __syncthreads();
  for (int o = 1; o < 256; o <<= 1) {
    int t = (tid >= o) ? buf[tid - o] : 0;
    __syncthreads();
    buf[tid] += t;
    __syncthreads();
  }
  if (tid < NB) {
    int excl = buf[tid] - v;
    bbase[tid] = excl;
    gcur[tid] = excl;
  }
  if (tid == 0) {
    bbase[NB] = NEDGES;
    offs[NNODES] = NEDGES;
  }
}

__global__ __launch_bounds__(256) void multisplit(const int* __restrict__ src,
                                                  const int* __restrict__ dst,
                                                  int* __restrict__ gcur,
                                                  uint2* __restrict__ gbuf) {
  __shared__ uint2 stage[NB * STAGE_CAP];  // 50176 B
  __shared__ int lcur[NB];
  int tid = threadIdx.x;
  if (tid < NB) lcur[tid] = 0;
  __syncthreads();
  int base = blockIdx.x * MS_EPB;
  for (int r = 0; r < MS_ROUNDS; ++r) {
    int off = r * 256 + tid;
    if (off < MS_EPB) {
      int k = base + off;
      int s = src[k], d = dst[k];
      int bk = d >> BSHIFT;
      int p = atomicAdd(&lcur[bk], 1);
      if (p < STAGE_CAP) {
        stage[bk * STAGE_CAP + p] = make_uint2((unsigned)s, (unsigned)d);
      } else {
        int g = atomicAdd(&gcur[bk], 1);
        gbuf[g] = make_uint2((unsigned)s, (unsigned)d);
      }
    }
    __syncthreads();
    if (tid < NB) {
      int n = lcur[tid];
      if (n > 0 && (n >= FLUSH_THRESH || r == MS_ROUNDS - 1)) {
        n = min(n, STAGE_CAP);
        int g = atomicAdd(&gcur[tid], n);
        for (int q = 0; q < n; ++q) gbuf[g + q] = stage[tid * STAGE_CAP + q];
        lcur[tid] = 0;
      }
    }
    __syncthreads();
  }
}

// one block per bucket: counting sort by local dst; emits csr_src, offs, dinv
__global__ __launch_bounds__(256) void bucket_sort(const uint2* __restrict__ gbuf,
                                                   const int* __restrict__ bhist,
                                                   const int* __restrict__ bbase,
                                                   int* __restrict__ csr_src,
                                                   int* __restrict__ offs,
                                                   float* __restrict__ dinv) {
  __shared__ int lhist[512];
  __shared__ int lscan[512];
  __shared__ int lcur2[512];
  __shared__ int lcsr[EB_CAP];
  int tid = threadIdx.x;
  int b = blockIdx.x;
  int ebase = bbase[b];
  int bsize = bhist[b];
  lhist[tid] = 0; lhist[tid + 256] = 0;
  lcur2[tid] = 0; lcur2[tid + 256] = 0;
  __syncthreads();
  for (int k = tid; k < bsize; k += 256)
    atomicAdd(&lhist[gbuf[ebase + k].y & 511], 1);
  __syncthreads();
  // inclusive scan of two independent 256-halves
  lscan[tid] = lhist[tid];
  lscan[tid + 256] = lhist[tid + 256];
  __syncthreads();
  for (int o = 1; o < 256; o <<= 1) {
    int a = (tid >= o) ? lscan[tid - o] : 0;
    int c = (tid >= o) ? lscan[256 + tid - o] : 0;
    __syncthreads();
    lscan[tid] += a;
    lscan[256 + tid] += c;
    __syncthreads();
  }
  int tot = lscan[255];
  __syncthreads();
  lscan[256 + tid] += tot;
  __syncthreads();
  // node outputs
  int nodebase = b << BSHIFT;
#pragma unroll
  for (int hh = 0; hh < 2; ++hh) {
    int l = hh * 256 + tid;
    int i = nodebase + l;
    if (i < NNODES) {
      int c = lhist[l];
      offs[i] = ebase + (lscan[l] - c);
      dinv[i] = rsqrtf((float)c + 1.0f);
    }
  }
  // scatter into LDS
  for (int k = tid; k < bsize; k += 256) {
    uint2 e = gbuf[ebase + k];
    int l = e.y & 511;
    int p = atomicAdd(&lcur2[l], 1);
    int pos = (lscan[l] - lhist[l]) + p;
    if (pos < EB_CAP) lcsr[pos] = (int)e.x;
  }
  __syncthreads();
  for (int k = tid; k < bsize; k += 256) csr_src[ebase + k] = lcsr[k];
}

// ---------------- encoder (writes bf16 h) ----------------

__global__ void encoder_kernel(const int* __restrict__ nt, const int* __restrict__ ninv,
                               const float* __restrict__ et, const float* __restrict__ ei,
                               ushort* __restrict__ h) {
  int idx = blockIdx.x * blockDim.x + threadIdx.x;
  if (idx >= NNODES * 32) return;
  int i = idx >> 5, d4 = (idx & 31) << 2;
  float4 a = *(const float4*)(et + nt[i] * DIM + d4);
  float4 b = *(const float4*)(ei + ninv[i] * DIM + d4);
  uint2 o;
  o.x = ((unsigned)f2bf(a.y + b.y) << 16) | f2bf(a.x + b.x);
  o.y = ((unsigned)f2bf(a.w + b.w) << 16) | f2bf(a.z + b.z);
  *(uint2*)(h + (size_t)i * DIM + d4) = o;
}

__global__ void wcvt_kernel(const float* __restrict__ w, ushort* __restrict__ o) {
  int idx = blockIdx.x * blockDim.x + threadIdx.x;
  if (idx < DIM * DIM) o[idx] = f2bf(w[idx]);
}

// ---------------- MFMA GEMM: xws = dinv * (h @ W) ----------------

__global__ __launch_bounds__(256) void gemm_kernel(const ushort* __restrict__ h,
                                                   const ushort* __restrict__ wb,
                                                   const float* __restrict__ dinv,
                                                   ushort* __restrict__ out) {
  __shared__ ushort Ws[32 * 64 * 8];  // B-fragment order
  int tid = threadIdx.x;
  for (int g = tid; g < 2048; g += 256) {
    int kt = g >> 6, l = g & 63;
    int ks = kt >> 3, t = kt & 7;
    int kb = ks * 32 + ((l >> 4) << 3);
    int col = t * 16 + (l & 15);
#pragma unroll
    for (int j = 0; j < 8; ++j) Ws[g * 8 + j] = wb[(kb + j) * DIM + col];
  }
  __syncthreads();
  int w = tid >> 6, lane = tid & 63;
  for (int tile = blockIdx.x * 4 + w; tile < NNODES / 16; tile += gridDim.x * 4) {
    int row0 = tile * 16;
    const ushort* hrow = h + (size_t)(row0 + (lane & 15)) * DIM + ((lane >> 4) << 3);
    f32x4 acc[8];
#pragma unroll
    for (int t = 0; t < 8; ++t) acc[t] = {0.f, 0.f, 0.f, 0.f};
#pragma unroll
    for (int ks = 0; ks < 4; ++ks) {
      bf16x8 a = *(const bf16x8*)(hrow + ks * 32);
#pragma unroll
      for (int t = 0; t < 8; ++t) {
        bf16x8 b = *(const bf16x8*)&Ws[((ks * 8 + t) * 64 + lane) * 8];
        acc[t] = __builtin_amdgcn_mfma_f32_16x16x32_bf16(a, b, acc[t], 0, 0, 0);
      }
    }
    int rbase = row0 + ((lane >> 4) << 2);
    int cbase = lane & 15;
    float4 dv = *(const float4*)(dinv + rbase);
    float dvr[4] = {dv.x, dv.y, dv.z, dv.w};
#pragma unroll
    for (int t = 0; t < 8; ++t)
#pragma unroll
      for (int r = 0; r < 4; ++r)
        out[(size_t)(rbase + r) * DIM + t * 16 + cbase] = f2bf(acc[t][r] * dvr[r]);
  }
}

// ---------------- aggregation: one wave per node, 16-deep gather ----------------

__global__ __launch_bounds__(256) void agg_kernel(const ushort* __restrict__ xws,
                                                  const int* __restrict__ offs,
                                                  const int* __restrict__ csr_src,
                                                  const float* __restrict__ dinv,
                                                  const float* __restrict__ bias,
                                                  ushort* __restrict__ outb,
                                                  float* __restrict__ outf, int relu) {
  int i = blockIdx.x * 4 + (threadIdx.x >> 6);
  if (i >= NNODES) return;
  int lane = threadIdx.x & 63;
  int s0 = offs[i], s1 = offs[i + 1];
  float ax = 0.f, ay = 0.f;
  int j = s0;
  for (; j + 16 <= s1; j += 16) {
    int s[16];
#pragma unroll
    for (int u = 0; u < 16; ++u) s[u] = csr_src[j + u];
    unsigned p[16];
#pragma unroll
    for (int u = 0; u < 16; ++u)
      p[u] = *(const unsigned*)(xws + (size_t)s[u] * DIM + lane * 2);
#pragma unroll
    for (int u = 0; u < 16; ++u) {
      ax += bf2f((ushort)(p[u] & 0xffffu));
      ay += bf2f((ushort)(p[u] >> 16));
    }
  }
  for (; j + 4 <= s1; j += 4) {
    int s[4];
#pragma unroll
    for (int u = 0; u < 4; ++u) s[u] = csr_src[j + u];
    unsigned p[4];
#pragma unroll
    for (int u = 0; u < 4; ++u)
      p[u] = *(const unsigned*)(xws + (size_t)s[u] * DIM + lane * 2);
#pragma unroll
    for (int u = 0; u < 4; ++u) {
      ax += bf2f((ushort)(p[u] & 0xffffu));
      ay += bf2f((ushort)(p[u] >> 16));
    }
  }
  for (; j < s1; ++j) {
    int sa = csr_src[j];
    unsigned pa = *(const unsigned*)(xws + (size_t)sa * DIM + lane * 2);
    ax += bf2f((ushort)(pa & 0xffffu));
    ay += bf2f((ushort)(pa >> 16));
  }
  unsigned ps = *(const unsigned*)(xws + (size_t)i * DIM + lane * 2);
  ax += bf2f((ushort)(ps & 0xffffu));
  ay += bf2f((ushort)(ps >> 16));
  float di = dinv[i];
  float2 b = *(const float2*)(bias + lane * 2);
  float vx = di * ax + b.x;
  float vy = di * ay + b.y;
  if (relu) { vx = fmaxf(vx, 0.f); vy = fmaxf(vy, 0.f); }
  if (outf) {
    *(float2*)(outf + (size_t)i * DIM + lane * 2) = make_float2(vx, vy);
  } else {
    *(unsigned*)(outb + (size_t)i * DIM + lane * 2) =
        ((unsigned)f2bf(vy) << 16) | f2bf(vx);
  }
}

// ---------------- readout ----------------

__global__ __launch_bounds__(128) void readout_kernel(const float* __restrict__ h,
                                                      const int* __restrict__ batch,
                                                      unsigned* __restrict__ gmaxk,
                                                      float* __restrict__ gsum) {
  int d = threadIdx.x;
  int start = blockIdx.x * 128;
  if (start >= NNODES) return;
  int end = min(start + 128, NNODES);
  int cur = batch[start];
  float s = 0.f, m = -INFINITY;
  for (int i = start; i < end; ++i) {
    int g = batch[i];
    float v = h[(size_t)i * DIM + d];
    if (g != cur) {
      atomicAdd(&gsum[cur * DIM + d], s);
      atomicMax(&gmaxk[cur * DIM + d], fkey(m));
      cur = g; s = 0.f; m = -INFINITY;
    }
    s += v;
    m = fmaxf(m, v);
  }
  atomicAdd(&gsum[cur * DIM + d], s);
  atomicMax(&gmaxk[cur * DIM + d], fkey(m));
}

__global__ void pack_kernel(const unsigned* __restrict__ gmaxk,
                            const float* __restrict__ gsum, float* __restrict__ out) {
  int idx = blockIdx.x * blockDim.x + threadIdx.x;
  if (idx >= NGRAPHS * 256) return;
  int g = idx >> 8, d = idx & 255;
  float v = (d < 128) ? fdecode(gmaxk[g * DIM + d]) : gsum[g * DIM + (d - 128)];
  out[idx] = rintf(v * 1000.0f) / 1000.0f;
}

// ---------------- launch ----------------

extern "C" void kernel_launch(void* const* d_in, const int* in_sizes, int n_in,
                              void* d_out, int out_size, void* d_ws, size_t ws_size,
                              hipStream_t stream) {
  const int* node_type = (const int*)d_in[0];
  const int* ninv      = (const int*)d_in[1];
  const int* edge      = (const int*)d_in[2];
  const int* batch     = (const int*)d_in[3];
  const float* emb_type = (const float*)d_in[4];
  const float* emb_inv  = (const float*)d_in[5];
  const float* Wp[3] = {(const float*)d_in[6], (const float*)d_in[8], (const float*)d_in[10]};
  const float* B[3] = {(const float*)d_in[7], (const float*)d_in[9], (const float*)d_in[11]};
  const int* srcp = edge;
  const int* dstp = edge + NEDGES;
  float* out = (float*)d_out;

  char* ws = (char*)d_ws;
  auto alloc = [&](size_t bytes) {
    char* p = ws;
    ws += (bytes + 255) & ~(size_t)255;
    return p;
  };
  ushort* hA     = (ushort*)alloc((size_t)NNODES * DIM * 2);
  ushort* xws    = (ushort*)alloc((size_t)NNODES * DIM * 2);
  float* h2f     = (float*)alloc((size_t)NNODES * DIM * 4);
  float* dinv    = (float*)alloc((size_t)NNODES * 4);
  int* offs      = (int*)alloc((size_t)(NNODES + 1) * 4);
  int* csr_src   = (int*)alloc((size_t)NEDGES * 4);
  uint2* gbuf    = (uint2*)alloc((size_t)NEDGES * 8);
  int* bhist     = (int*)alloc((size_t)NB * 4);
  int* bbase     = (int*)alloc((size_t)(NB + 1) * 4);
  int* gcur      = (int*)alloc((size_t)NB * 4);
  ushort* wbf    = (ushort*)alloc((size_t)3 * DIM * DIM * 2);
  unsigned* gmaxk = (unsigned*)alloc((size_t)NGRAPHS * DIM * 4);
  float* gsum    = (float*)alloc((size_t)NGRAPHS * DIM * 4);

  hipMemsetAsync(bhist, 0, (size_t)NB * 4, stream);
  hipMemsetAsync(gmaxk, 0, (size_t)NGRAPHS * DIM * 4, stream);
  hipMemsetAsync(gsum, 0, (size_t)NGRAPHS * DIM * 4, stream);

  bucket_hist<<<BH_BLOCKS, 256, 0, stream>>>(dstp, bhist);
  bucket_scan<<<1, 256, 0, stream>>>(bhist, bbase, gcur, offs);
  multisplit<<<MS_BLOCKS, 256, 0, stream>>>(srcp, dstp, gcur, gbuf);
  bucket_sort<<<NB, 256, 0, stream>>>(gbuf, bhist, bbase, csr_src, offs, dinv);

  for (int l = 0; l < 3; ++l)
    wcvt_kernel<<<64, 256, 0, stream>>>(Wp[l], wbf + (size_t)l * DIM * DIM);
  encoder_kernel<<<NNODES * 32 / 256, 256, 0, stream>>>(node_type, ninv, emb_type, emb_inv, hA);

  for (int l = 0; l < 3; ++l) {
    gemm_kernel<<<256, 256, 0, stream>>>(hA, wbf + (size_t)l * DIM * DIM, dinv, xws);
    agg_kernel<<<NNODES / 4, 256, 0, stream>>>(xws, offs, csr_src, dinv, B[l],
                                               hA, (l == 2) ? h2f : nullptr, l < 2 ? 1 : 0);
  }

  readout_kernel<<<(NNODES + 127) / 128, 128, 0, stream>>>(h2f, batch, gmaxk, gsum);
  pack_kernel<<<64, 256, 0, stream>>>(gmaxk, gsum, out);
}

// Round 5
// 343.317 us; speedup vs baseline: 3.7914x; 1.1689x over previous
//
#include <hip/hip_runtime.h>
#include <hip/hip_bf16.h>
#include <cstdint>

#define NNODES 100000
#define NEDGES 1600000
#define NGRAPHS 64
#define DIM 128

#define NB 196          // buckets: dst >> 9 (512 nodes each)
#define BSHIFT 9
#define MS_CAP 64
#define MS_FLUSH 32
#define MS_BLOCKS 200
#define MS_EPB (NEDGES / MS_BLOCKS)        // 8000
#define MS_ROUNDS ((MS_EPB + 1023) / 1024) // 8
#define BH_BLOCKS 200
#define BH_EPB (NEDGES / BH_BLOCKS)        // 8000
#define EB_CAP 10000                       // max edges per bucket (mean 8163)

typedef __attribute__((ext_vector_type(8))) short bf16x8;
typedef __attribute__((ext_vector_type(4))) float f32x4;

__device__ inline ushort f2bf(float f) {
  __hip_bfloat16 h = __float2bfloat16(f);
  return __builtin_bit_cast(ushort, h);
}
__device__ inline float bf2f(ushort u) {
  return __uint_as_float(((unsigned)u) << 16);
}
__device__ inline unsigned fkey(float f) {
  unsigned b = __float_as_uint(f);
  return (b & 0x80000000u) ? ~b : (b | 0x80000000u);
}
__device__ inline float fdecode(unsigned k) {
  unsigned b = (k & 0x80000000u) ? (k & 0x7FFFFFFFu) : ~k;
  return __uint_as_float(b);
}

// ---------------- preprocessing: bucketed counting sort (uint32-packed) ----------------
// record = src (17 bits) | local_dst (9 bits) << 17

__global__ __launch_bounds__(256) void bucket_hist(const int* __restrict__ dst,
                                                   int* __restrict__ bhist) {
  __shared__ int bh[NB];
  int tid = threadIdx.x;
  if (tid < NB) bh[tid] = 0;
  __syncthreads();
  int base = blockIdx.x * BH_EPB;
  for (int o = tid * 4; o < BH_EPB; o += 1024) {
    int4 d4 = *(const int4*)(dst + base + o);
    atomicAdd(&bh[d4.x >> BSHIFT], 1);
    atomicAdd(&bh[d4.y >> BSHIFT], 1);
    atomicAdd(&bh[d4.z >> BSHIFT], 1);
    atomicAdd(&bh[d4.w >> BSHIFT], 1);
  }
  __syncthreads();
  if (tid < NB && bh[tid]) atomicAdd(&bhist[tid], bh[tid]);
}

__global__ __launch_bounds__(256) void bucket_scan(const int* __restrict__ bhist,
                                                   int* __restrict__ bbase,
                                                   int* __restrict__ gcur,
                                                   int* __restrict__ offs) {
  __shared__ int buf[256];
  int tid = threadIdx.x;
  int v = (tid < NB) ? bhist[tid] : 0;
  buf[tid] = v;
  __syncthreads();
  for (int o = 1; o < 256; o <<= 1) {
    int t = (tid >= o) ? buf[tid - o] : 0;
    __syncthreads();
    buf[tid] += t;
    __syncthreads();
  }
  if (tid < NB) {
    int excl = buf[tid] - v;
    bbase[tid] = excl;
    gcur[tid] = excl;
  }
  if (tid == 0) {
    bbase[NB] = NEDGES;
    offs[NNODES] = NEDGES;
  }
}

__global__ __launch_bounds__(256) void multisplit(const int* __restrict__ src,
                                                  const int* __restrict__ dst,
                                                  int* __restrict__ gcur,
                                                  unsigned* __restrict__ gbuf) {
  __shared__ unsigned stage[NB * MS_CAP];  // 50176 B
  __shared__ int lcur[NB];
  int tid = threadIdx.x;
  if (tid < NB) lcur[tid] = 0;
  __syncthreads();
  int base = blockIdx.x * MS_EPB;
  for (int r = 0; r < MS_ROUNDS; ++r) {
    int off = (r * 256 + tid) * 4;
    if (off < MS_EPB) {
      int4 s4 = *(const int4*)(src + base + off);
      int4 d4 = *(const int4*)(dst + base + off);
      int ss[4] = {s4.x, s4.y, s4.z, s4.w};
      int dd[4] = {d4.x, d4.y, d4.z, d4.w};
#pragma unroll
      for (int u = 0; u < 4; ++u) {
        int bk = dd[u] >> BSHIFT;
        unsigned rec = (unsigned)ss[u] | ((unsigned)(dd[u] & 511) << 17);
        int p = atomicAdd(&lcur[bk], 1);
        if (p < MS_CAP) stage[bk * MS_CAP + p] = rec;
        else { int g = atomicAdd(&gcur[bk], 1); gbuf[g] = rec; }
      }
    }
    __syncthreads();
    if (tid < NB) {
      int n = lcur[tid];
      if (n > 0 && (n >= MS_FLUSH || r == MS_ROUNDS - 1)) {
        n = min(n, MS_CAP);
        int g = atomicAdd(&gcur[tid], n);
        for (int q = 0; q < n; ++q) gbuf[g + q] = stage[tid * MS_CAP + q];
        lcur[tid] = 0;
      }
    }
    __syncthreads();
  }
}

// one block per bucket: counting sort by local dst; emits csr_src, offs, dinv
__global__ __launch_bounds__(256) void bucket_sort(const unsigned* __restrict__ gbuf,
                                                   const int* __restrict__ bhist,
                                                   const int* __restrict__ bbase,
                                                   int* __restrict__ csr_src,
                                                   int* __restrict__ offs,
                                                   float* __restrict__ dinv) {
  __shared__ int lhist[512];
  __shared__ int lscan[512];
  __shared__ int lcur2[512];
  __shared__ int lcsr[EB_CAP];
  int tid = threadIdx.x;
  int b = blockIdx.x;
  int ebase = bbase[b];
  int bsize = bhist[b];
  lhist[tid] = 0; lhist[tid + 256] = 0;
  lcur2[tid] = 0; lcur2[tid + 256] = 0;
  __syncthreads();
  for (int k = tid; k < bsize; k += 256)
    atomicAdd(&lhist[(gbuf[ebase + k] >> 17) & 511], 1);
  __syncthreads();
  lscan[tid] = lhist[tid];
  lscan[tid + 256] = lhist[tid + 256];
  __syncthreads();
  for (int o = 1; o < 256; o <<= 1) {
    int a = (tid >= o) ? lscan[tid - o] : 0;
    int c = (tid >= o) ? lscan[256 + tid - o] : 0;
    __syncthreads();
    lscan[tid] += a;
    lscan[256 + tid] += c;
    __syncthreads();
  }
  int tot = lscan[255];
  __syncthreads();
  lscan[256 + tid] += tot;
  __syncthreads();
  int nodebase = b << BSHIFT;
#pragma unroll
  for (int hh = 0; hh < 2; ++hh) {
    int l = hh * 256 + tid;
    int i = nodebase + l;
    if (i < NNODES) {
      int c = lhist[l];
      offs[i] = ebase + (lscan[l] - c);
      dinv[i] = rsqrtf((float)c + 1.0f);
    }
  }
  for (int k = tid; k < bsize; k += 256) {
    unsigned e = gbuf[ebase + k];
    int l = (e >> 17) & 511;
    int p = atomicAdd(&lcur2[l], 1);
    int pos = (lscan[l] - lhist[l]) + p;
    if (pos < EB_CAP) lcsr[pos] = (int)(e & 0x1FFFFu);
  }
  __syncthreads();
  for (int k = tid; k < bsize; k += 256) csr_src[ebase + k] = lcsr[k];
}

// ---------------- layer-0 shortcut: TW = [emb_type;emb_inv] @ W0 (f32) ----------------

__global__ __launch_bounds__(128) void embW0_kernel(const float* __restrict__ et,
                                                    const float* __restrict__ ei,
                                                    const float* __restrict__ W0,
                                                    float* __restrict__ TW) {
  int r = blockIdx.x;  // 0..6
  int c = threadIdx.x;
  const float* in = (r < 4) ? (et + r * DIM) : (ei + (r - 4) * DIM);
  float acc = 0.f;
  for (int k = 0; k < DIM; ++k) acc += in[k] * W0[k * DIM + c];
  TW[r * DIM + c] = acc;
}

// xws0[i] = dinv[i] * (TW[nt[i]] + TW[4+ninv[i]])  -> bf16
__global__ void xws0_kernel(const int* __restrict__ nt, const int* __restrict__ ninv,
                            const float* __restrict__ TW, const float* __restrict__ dinv,
                            ushort* __restrict__ xws) {
  int idx = blockIdx.x * blockDim.x + threadIdx.x;
  if (idx >= NNODES * 32) return;
  int i = idx >> 5, d4 = (idx & 31) << 2;
  float4 a = *(const float4*)(TW + nt[i] * DIM + d4);
  float4 b = *(const float4*)(TW + (4 + ninv[i]) * DIM + d4);
  float di = dinv[i];
  uint2 o;
  o.x = ((unsigned)f2bf((a.y + b.y) * di) << 16) | f2bf((a.x + b.x) * di);
  o.y = ((unsigned)f2bf((a.w + b.w) * di) << 16) | f2bf((a.z + b.z) * di);
  *(uint2*)(xws + (size_t)i * DIM + d4) = o;
}

__global__ void wcvt_kernel(const float* __restrict__ w, ushort* __restrict__ o) {
  int idx = blockIdx.x * blockDim.x + threadIdx.x;
  if (idx < DIM * DIM) o[idx] = f2bf(w[idx]);
}

// ---------------- MFMA GEMM: xws = dinv * (h @ W) ----------------

__global__ __launch_bounds__(256) void gemm_kernel(const ushort* __restrict__ h,
                                                   const ushort* __restrict__ wb,
                                                   const float* __restrict__ dinv,
                                                   ushort* __restrict__ out) {
  __shared__ ushort Ws[32 * 64 * 8];  // B-fragment order
  int tid = threadIdx.x;
  for (int g = tid; g < 2048; g += 256) {
    int kt = g >> 6, l = g & 63;
    int ks = kt >> 3, t = kt & 7;
    int kb = ks * 32 + ((l >> 4) << 3);
    int col = t * 16 + (l & 15);
#pragma unroll
    for (int j = 0; j < 8; ++j) Ws[g * 8 + j] = wb[(kb + j) * DIM + col];
  }
  __syncthreads();
  int w = tid >> 6, lane = tid & 63;
  for (int tile = blockIdx.x * 4 + w; tile < NNODES / 16; tile += gridDim.x * 4) {
    int row0 = tile * 16;
    const ushort* hrow = h + (size_t)(row0 + (lane & 15)) * DIM + ((lane >> 4) << 3);
    f32x4 acc[8];
#pragma unroll
    for (int t = 0; t < 8; ++t) acc[t] = {0.f, 0.f, 0.f, 0.f};
#pragma unroll
    for (int ks = 0; ks < 4; ++ks) {
      bf16x8 a = *(const bf16x8*)(hrow + ks * 32);
#pragma unroll
      for (int t = 0; t < 8; ++t) {
        bf16x8 b = *(const bf16x8*)&Ws[((ks * 8 + t) * 64 + lane) * 8];
        acc[t] = __builtin_amdgcn_mfma_f32_16x16x32_bf16(a, b, acc[t], 0, 0, 0);
      }
    }
    int rbase = row0 + ((lane >> 4) << 2);
    int cbase = lane & 15;
    float4 dv = *(const float4*)(dinv + rbase);
    float dvr[4] = {dv.x, dv.y, dv.z, dv.w};
#pragma unroll
    for (int t = 0; t < 8; ++t)
#pragma unroll
      for (int r = 0; r < 4; ++r)
        out[(size_t)(rbase + r) * DIM + t * 16 + cbase] = f2bf(acc[t][r] * dvr[r]);
  }
}

// ---------------- aggregation: one wave per node, 16-deep gather ----------------

__global__ __launch_bounds__(256, 8) void agg_kernel(const ushort* __restrict__ xws,
                                                     const int* __restrict__ offs,
                                                     const int* __restrict__ csr_src,
                                                     const float* __restrict__ dinv,
                                                     const float* __restrict__ bias,
                                                     ushort* __restrict__ outb,
                                                     float* __restrict__ outf, int relu) {
  int i = blockIdx.x * 4 + (threadIdx.x >> 6);
  if (i >= NNODES) return;
  int lane = threadIdx.x & 63;
  int s0 = offs[i], s1 = offs[i + 1];
  float ax = 0.f, ay = 0.f;
  int j = s0;
  for (; j + 16 <= s1; j += 16) {
    int s[16];
#pragma unroll
    for (int u = 0; u < 16; ++u) s[u] = csr_src[j + u];
    unsigned p[16];
#pragma unroll
    for (int u = 0; u < 16; ++u)
      p[u] = *(const unsigned*)(xws + (size_t)s[u] * DIM + lane * 2);
#pragma unroll
    for (int u = 0; u < 16; ++u) {
      ax += bf2f((ushort)(p[u] & 0xffffu));
      ay += bf2f((ushort)(p[u] >> 16));
    }
  }
  for (; j + 4 <= s1; j += 4) {
    int s[4];
#pragma unroll
    for (int u = 0; u < 4; ++u) s[u] = csr_src[j + u];
    unsigned p[4];
#pragma unroll
    for (int u = 0; u < 4; ++u)
      p[u] = *(const unsigned*)(xws + (size_t)s[u] * DIM + lane * 2);
#pragma unroll
    for (int u = 0; u < 4; ++u) {
      ax += bf2f((ushort)(p[u] & 0xffffu));
      ay += bf2f((ushort)(p[u] >> 16));
    }
  }
  for (; j < s1; ++j) {
    int sa = csr_src[j];
    unsigned pa = *(const unsigned*)(xws + (size_t)sa * DIM + lane * 2);
    ax += bf2f((ushort)(pa & 0xffffu));
    ay += bf2f((ushort)(pa >> 16));
  }
  unsigned ps = *(const unsigned*)(xws + (size_t)i * DIM + lane * 2);
  ax += bf2f((ushort)(ps & 0xffffu));
  ay += bf2f((ushort)(ps >> 16));
  float di = dinv[i];
  float2 b = *(const float2*)(bias + lane * 2);
  float vx = di * ax + b.x;
  float vy = di * ay + b.y;
  if (relu) { vx = fmaxf(vx, 0.f); vy = fmaxf(vy, 0.f); }
  if (outf) {
    *(float2*)(outf + (size_t)i * DIM + lane * 2) = make_float2(vx, vy);
  } else {
    *(unsigned*)(outb + (size_t)i * DIM + lane * 2) =
        ((unsigned)f2bf(vy) << 16) | f2bf(vx);
  }
}

// ---------------- readout ----------------

__global__ __launch_bounds__(128) void readout_kernel(const float* __restrict__ h,
                                                      const int* __restrict__ batch,
                                                      unsigned* __restrict__ gmaxk,
                                                      float* __restrict__ gsum) {
  int d = threadIdx.x;
  int start = blockIdx.x * 128;
  if (start >= NNODES) return;
  int end = min(start + 128, NNODES);
  int cur = batch[start];
  float s = 0.f, m = -INFINITY;
  for (int i = start; i < end; ++i) {
    int g = batch[i];
    float v = h[(size_t)i * DIM + d];
    if (g != cur) {
      atomicAdd(&gsum[cur * DIM + d], s);
      atomicMax(&gmaxk[cur * DIM + d], fkey(m));
      cur = g; s = 0.f; m = -INFINITY;
    }
    s += v;
    m = fmaxf(m, v);
  }
  atomicAdd(&gsum[cur * DIM + d], s);
  atomicMax(&gmaxk[cur * DIM + d], fkey(m));
}

__global__ void pack_kernel(const unsigned* __restrict__ gmaxk,
                            const float* __restrict__ gsum, float* __restrict__ out) {
  int idx = blockIdx.x * blockDim.x + threadIdx.x;
  if (idx >= NGRAPHS * 256) return;
  int g = idx >> 8, d = idx & 255;
  float v = (d < 128) ? fdecode(gmaxk[g * DIM + d]) : gsum[g * DIM + (d - 128)];
  out[idx] = rintf(v * 1000.0f) / 1000.0f;
}

// ---------------- launch ----------------

extern "C" void kernel_launch(void* const* d_in, const int* in_sizes, int n_in,
                              void* d_out, int out_size, void* d_ws, size_t ws_size,
                              hipStream_t stream) {
  const int* node_type = (const int*)d_in[0];
  const int* ninv      = (const int*)d_in[1];
  const int* edge      = (const int*)d_in[2];
  const int* batch     = (const int*)d_in[3];
  const float* emb_type = (const float*)d_in[4];
  const float* emb_inv  = (const float*)d_in[5];
  const float* W0 = (const float*)d_in[6];
  const float* B[3] = {(const float*)d_in[7], (const float*)d_in[9], (const float*)d_in[11]};
  const float* W12[2] = {(const float*)d_in[8], (const float*)d_in[10]};
  const int* srcp = edge;
  const int* dstp = edge + NEDGES;
  float* out = (float*)d_out;

  char* ws = (char*)d_ws;
  auto alloc = [&](size_t bytes) {
    char* p = ws;
    ws += (bytes + 255) & ~(size_t)255;
    return p;
  };
  ushort* hA     = (ushort*)alloc((size_t)NNODES * DIM * 2);
  ushort* xws    = (ushort*)alloc((size_t)NNODES * DIM * 2);
  float* h2f     = (float*)alloc((size_t)NNODES * DIM * 4);
  float* dinv    = (float*)alloc((size_t)NNODES * 4);
  int* offs      = (int*)alloc((size_t)(NNODES + 1) * 4);
  int* csr_src   = (int*)alloc((size_t)NEDGES * 4);
  unsigned* gbuf = (unsigned*)alloc((size_t)NEDGES * 4);
  unsigned* gmaxk = (unsigned*)alloc((size_t)NGRAPHS * DIM * 4);   // contiguous with
  float* gsum    = (float*)alloc((size_t)NGRAPHS * DIM * 4);       // gsum and bhist
  int* bhist     = (int*)alloc((size_t)NB * 4);
  int* bbase     = (int*)alloc((size_t)(NB + 1) * 4);
  int* gcur      = (int*)alloc((size_t)NB * 4);
  float* TW      = (float*)alloc((size_t)7 * DIM * 4);
  ushort* wbf    = (ushort*)alloc((size_t)2 * DIM * DIM * 2);

  // gmaxk | gsum | bhist are contiguous (both 32 KiB, multiples of 256 B)
  hipMemsetAsync(gmaxk, 0, (size_t)NGRAPHS * DIM * 4 * 2 + NB * 4, stream);

  bucket_hist<<<BH_BLOCKS, 256, 0, stream>>>(dstp, bhist);
  bucket_scan<<<1, 256, 0, stream>>>(bhist, bbase, gcur, offs);
  multisplit<<<MS_BLOCKS, 256, 0, stream>>>(srcp, dstp, gcur, gbuf);
  bucket_sort<<<NB, 256, 0, stream>>>(gbuf, bhist, bbase, csr_src, offs, dinv);

  embW0_kernel<<<7, 128, 0, stream>>>(emb_type, emb_inv, W0, TW);
  wcvt_kernel<<<64, 256, 0, stream>>>(W12[0], wbf);
  wcvt_kernel<<<64, 256, 0, stream>>>(W12[1], wbf + (size_t)DIM * DIM);
  xws0_kernel<<<NNODES * 32 / 256, 256, 0, stream>>>(node_type, ninv, TW, dinv, xws);

  for (int l = 0; l < 3; ++l) {
    if (l > 0)
      gemm_kernel<<<256, 256, 0, stream>>>(hA, wbf + (size_t)(l - 1) * DIM * DIM, dinv, xws);
    agg_kernel<<<NNODES / 4, 256, 0, stream>>>(xws, offs, csr_src, dinv, B[l],
                                               hA, (l == 2) ? h2f : nullptr, l < 2 ? 1 : 0);
  }

  readout_kernel<<<(NNODES + 127) / 128, 128, 0, stream>>>(h2f, batch, gmaxk, gsum);
  pack_kernel<<<64, 256, 0, stream>>>(gmaxk, gsum, out);
}

// Round 6
// 332.579 us; speedup vs baseline: 3.9138x; 1.0323x over previous
//
#include <hip/hip_runtime.h>
#include <hip/hip_bf16.h>
#include <cstdint>

#define NNODES 100000
#define NEDGES 1600000
#define NGRAPHS 64
#define DIM 128

#define NB 196          // buckets: dst >> 9 (512 nodes each)
#define BSHIFT 9
#define SC_BLOCKS 200
#define SC_EPB (NEDGES / SC_BLOCKS)        // 8000
#define EB_CAP 10000                       // max edges per bucket (mean 8163)

typedef __attribute__((ext_vector_type(8))) short bf16x8;
typedef __attribute__((ext_vector_type(4))) float f32x4;

__device__ inline ushort f2bf(float f) {
  __hip_bfloat16 h = __float2bfloat16(f);
  return __builtin_bit_cast(ushort, h);
}
__device__ inline float bf2f(ushort u) {
  return __uint_as_float(((unsigned)u) << 16);
}
__device__ inline unsigned fkey(float f) {
  unsigned b = __float_as_uint(f);
  return (b & 0x80000000u) ? ~b : (b | 0x80000000u);
}
__device__ inline float fdecode(unsigned k) {
  unsigned b = (k & 0x80000000u) ? (k & 0x7FFFFFFFu) : ~k;
  return __uint_as_float(b);
}

// ---------------- preprocessing: 2-pass deterministic bucket scatter ----------------
// record = src (17 bits) | local_dst (9 bits) << 17

__global__ __launch_bounds__(256) void hist2_kernel(const int* __restrict__ dst,
                                                    int* __restrict__ blockhist,
                                                    int* __restrict__ bhist) {
  __shared__ int bh[NB];
  int tid = threadIdx.x;
  if (tid < NB) bh[tid] = 0;
  __syncthreads();
  int base = blockIdx.x * SC_EPB;
  for (int o = tid * 4; o < SC_EPB; o += 1024) {
    int4 d4 = *(const int4*)(dst + base + o);
    atomicAdd(&bh[d4.x >> BSHIFT], 1);
    atomicAdd(&bh[d4.y >> BSHIFT], 1);
    atomicAdd(&bh[d4.z >> BSHIFT], 1);
    atomicAdd(&bh[d4.w >> BSHIFT], 1);
  }
  __syncthreads();
  if (tid < NB) {
    blockhist[blockIdx.x * NB + tid] = bh[tid];
    if (bh[tid]) atomicAdd(&bhist[tid], bh[tid]);
  }
}

// 1 block: bucket-level exclusive scan + per-(block,bucket) base matrix
__global__ __launch_bounds__(256) void scan2_kernel(const int* __restrict__ bhist,
                                                    const int* __restrict__ blockhist,
                                                    int* __restrict__ bbase,
                                                    int* __restrict__ blockbase,
                                                    int* __restrict__ offs) {
  __shared__ int buf[256];
  int tid = threadIdx.x;
  int v = (tid < NB) ? bhist[tid] : 0;
  buf[tid] = v;
  __syncthreads();
  for (int o = 1; o < 256; o <<= 1) {
    int t = (tid >= o) ? buf[tid - o] : 0;
    __syncthreads();
    buf[tid] += t;
    __syncthreads();
  }
  int excl = buf[tid] - v;
  if (tid < NB) {
    bbase[tid] = excl;
    int run = excl;
    for (int blk = 0; blk < SC_BLOCKS; ++blk) {
      int idx = blk * NB + tid;
      int c = blockhist[idx];
      blockbase[idx] = run;
      run += c;
    }
  }
  if (tid == 0) {
    bbase[NB] = NEDGES;
    offs[NNODES] = NEDGES;
  }
}

__global__ __launch_bounds__(256) void scatter2_kernel(const int* __restrict__ src,
                                                       const int* __restrict__ dst,
                                                       const int* __restrict__ blockbase,
                                                       unsigned* __restrict__ gbuf) {
  __shared__ int lcur[NB];
  int tid = threadIdx.x;
  if (tid < NB) lcur[tid] = blockbase[blockIdx.x * NB + tid];
  __syncthreads();
  int base = blockIdx.x * SC_EPB;
  for (int o = tid * 4; o < SC_EPB; o += 1024) {
    int4 s4 = *(const int4*)(src + base + o);
    int4 d4 = *(const int4*)(dst + base + o);
    int ss[4] = {s4.x, s4.y, s4.z, s4.w};
    int dd[4] = {d4.x, d4.y, d4.z, d4.w};
#pragma unroll
    for (int u = 0; u < 4; ++u) {
      int bk = dd[u] >> BSHIFT;
      unsigned rec = (unsigned)ss[u] | ((unsigned)(dd[u] & 511) << 17);
      int pos = atomicAdd(&lcur[bk], 1);
      gbuf[pos] = rec;
    }
  }
}

// one block per bucket: counting sort by local dst; emits csr_src, offs, dinv
__global__ __launch_bounds__(256) void bucket_sort(const unsigned* __restrict__ gbuf,
                                                   const int* __restrict__ bhist,
                                                   const int* __restrict__ bbase,
                                                   int* __restrict__ csr_src,
                                                   int* __restrict__ offs,
                                                   float* __restrict__ dinv) {
  __shared__ int lhist[512];
  __shared__ int lscan[512];
  __shared__ int lcur2[512];
  __shared__ int lcsr[EB_CAP];
  int tid = threadIdx.x;
  int b = blockIdx.x;
  int ebase = bbase[b];
  int bsize = bhist[b];
  lhist[tid] = 0; lhist[tid + 256] = 0;
  lcur2[tid] = 0; lcur2[tid + 256] = 0;
  __syncthreads();
  for (int k = tid; k < bsize; k += 256)
    atomicAdd(&lhist[(gbuf[ebase + k] >> 17) & 511], 1);
  __syncthreads();
  lscan[tid] = lhist[tid];
  lscan[tid + 256] = lhist[tid + 256];
  __syncthreads();
  for (int o = 1; o < 256; o <<= 1) {
    int a = (tid >= o) ? lscan[tid - o] : 0;
    int c = (tid >= o) ? lscan[256 + tid - o] : 0;
    __syncthreads();
    lscan[tid] += a;
    lscan[256 + tid] += c;
    __syncthreads();
  }
  int tot = lscan[255];
  __syncthreads();
  lscan[256 + tid] += tot;
  __syncthreads();
  int nodebase = b << BSHIFT;
#pragma unroll
  for (int hh = 0; hh < 2; ++hh) {
    int l = hh * 256 + tid;
    int i = nodebase + l;
    if (i < NNODES) {
      int c = lhist[l];
      offs[i] = ebase + (lscan[l] - c);
      dinv[i] = rsqrtf((float)c + 1.0f);
    }
  }
  for (int k = tid; k < bsize; k += 256) {
    unsigned e = gbuf[ebase + k];
    int l = (e >> 17) & 511;
    int p = atomicAdd(&lcur2[l], 1);
    int pos = (lscan[l] - lhist[l]) + p;
    if (pos < EB_CAP) lcsr[pos] = (int)(e & 0x1FFFFu);
  }
  __syncthreads();
  for (int k = tid; k < bsize; k += 256) csr_src[ebase + k] = lcsr[k];
}

// ---------------- fused prep: TW = [emb_type;emb_inv]@W0 (f32) + W1/W2 -> bf16 ----------------
// blocks 0..6: embW0 rows; blocks 7..22: W1 cvt; blocks 23..38: W2 cvt. 128 threads.

__global__ __launch_bounds__(128) void prep_kernel(const float* __restrict__ et,
                                                   const float* __restrict__ ei,
                                                   const float* __restrict__ W0,
                                                   const float* __restrict__ W1,
                                                   const float* __restrict__ W2,
                                                   float* __restrict__ TW,
                                                   ushort* __restrict__ wbf) {
  int b = blockIdx.x;
  int tid = threadIdx.x;
  if (b < 7) {
    const float* in = (b < 4) ? (et + b * DIM) : (ei + (b - 4) * DIM);
    float acc = 0.f;
    for (int k = 0; k < DIM; ++k) acc += in[k] * W0[k * DIM + tid];
    TW[b * DIM + tid] = acc;
  } else {
    int m = (b - 7) >> 4;               // 0: W1, 1: W2
    int blk = (b - 7) & 15;
    const float* w = m ? W2 : W1;
    ushort* o = wbf + (size_t)m * DIM * DIM;
    int base = blk * 1024 + tid * 8;
    float4 a = *(const float4*)(w + base);
    float4 c = *(const float4*)(w + base + 4);
    uint4 r;
    r.x = ((unsigned)f2bf(a.y) << 16) | f2bf(a.x);
    r.y = ((unsigned)f2bf(a.w) << 16) | f2bf(a.z);
    r.z = ((unsigned)f2bf(c.y) << 16) | f2bf(c.x);
    r.w = ((unsigned)f2bf(c.w) << 16) | f2bf(c.z);
    *(uint4*)(o + base) = r;
  }
}

// xws0[i] = dinv[i] * (TW[nt[i]] + TW[4+ninv[i]])  -> bf16
__global__ void xws0_kernel(const int* __restrict__ nt, const int* __restrict__ ninv,
                            const float* __restrict__ TW, const float* __restrict__ dinv,
                            ushort* __restrict__ xws) {
  int idx = blockIdx.x * blockDim.x + threadIdx.x;
  if (idx >= NNODES * 32) return;
  int i = idx >> 5, d4 = (idx & 31) << 2;
  float4 a = *(const float4*)(TW + nt[i] * DIM + d4);
  float4 b = *(const float4*)(TW + (4 + ninv[i]) * DIM + d4);
  float di = dinv[i];
  uint2 o;
  o.x = ((unsigned)f2bf((a.y + b.y) * di) << 16) | f2bf((a.x + b.x) * di);
  o.y = ((unsigned)f2bf((a.w + b.w) * di) << 16) | f2bf((a.z + b.z) * di);
  *(uint2*)(xws + (size_t)i * DIM + d4) = o;
}

// ---------------- MFMA GEMM: xws = dinv * (h @ W) ----------------

__global__ __launch_bounds__(256) void gemm_kernel(const ushort* __restrict__ h,
                                                   const ushort* __restrict__ wb,
                                                   const float* __restrict__ dinv,
                                                   ushort* __restrict__ out) {
  __shared__ ushort Ws[32 * 64 * 8];  // B-fragment order
  int tid = threadIdx.x;
  for (int g = tid; g < 2048; g += 256) {
    int kt = g >> 6, l = g & 63;
    int ks = kt >> 3, t = kt & 7;
    int kb = ks * 32 + ((l >> 4) << 3);
    int col = t * 16 + (l & 15);
#pragma unroll
    for (int j = 0; j < 8; ++j) Ws[g * 8 + j] = wb[(kb + j) * DIM + col];
  }
  __syncthreads();
  int w = tid >> 6, lane = tid & 63;
  for (int tile = blockIdx.x * 4 + w; tile < NNODES / 16; tile += gridDim.x * 4) {
    int row0 = tile * 16;
    const ushort* hrow = h + (size_t)(row0 + (lane & 15)) * DIM + ((lane >> 4) << 3);
    f32x4 acc[8];
#pragma unroll
    for (int t = 0; t < 8; ++t) acc[t] = {0.f, 0.f, 0.f, 0.f};
#pragma unroll
    for (int ks = 0; ks < 4; ++ks) {
      bf16x8 a = *(const bf16x8*)(hrow + ks * 32);
#pragma unroll
      for (int t = 0; t < 8; ++t) {
        bf16x8 b = *(const bf16x8*)&Ws[((ks * 8 + t) * 64 + lane) * 8];
        acc[t] = __builtin_amdgcn_mfma_f32_16x16x32_bf16(a, b, acc[t], 0, 0, 0);
      }
    }
    int rbase = row0 + ((lane >> 4) << 2);
    int cbase = lane & 15;
    float4 dv = *(const float4*)(dinv + rbase);
    float dvr[4] = {dv.x, dv.y, dv.z, dv.w};
#pragma unroll
    for (int t = 0; t < 8; ++t)
#pragma unroll
      for (int r = 0; r < 4; ++r)
        out[(size_t)(rbase + r) * DIM + t * 16 + cbase] = f2bf(acc[t][r] * dvr[r]);
  }
}

// ---------------- aggregation: one wave per node, 16-deep gather ----------------

__global__ __launch_bounds__(256, 8) void agg_kernel(const ushort* __restrict__ xws,
                                                     const int* __restrict__ offs,
                                                     const int* __restrict__ csr_src,
                                                     const float* __restrict__ dinv,
                                                     const float* __restrict__ bias,
                                                     ushort* __restrict__ outb, int relu) {
  int i = blockIdx.x * 4 + (threadIdx.x >> 6);
  if (i >= NNODES) return;
  int lane = threadIdx.x & 63;
  int s0 = offs[i], s1 = offs[i + 1];
  float ax = 0.f, ay = 0.f;
  int j = s0;
  for (; j + 16 <= s1; j += 16) {
    int s[16];
#pragma unroll
    for (int u = 0; u < 16; ++u) s[u] = csr_src[j + u];
    unsigned p[16];
#pragma unroll
    for (int u = 0; u < 16; ++u)
      p[u] = *(const unsigned*)(xws + (size_t)s[u] * DIM + lane * 2);
#pragma unroll
    for (int u = 0; u < 16; ++u) {
      ax += bf2f((ushort)(p[u] & 0xffffu));
      ay += bf2f((ushort)(p[u] >> 16));
    }
  }
  for (; j + 4 <= s1; j += 4) {
    int s[4];
#pragma unroll
    for (int u = 0; u < 4; ++u) s[u] = csr_src[j + u];
    unsigned p[4];
#pragma unroll
    for (int u = 0; u < 4; ++u)
      p[u] = *(const unsigned*)(xws + (size_t)s[u] * DIM + lane * 2);
#pragma unroll
    for (int u = 0; u < 4; ++u) {
      ax += bf2f((ushort)(p[u] & 0xffffu));
      ay += bf2f((ushort)(p[u] >> 16));
    }
  }
  for (; j < s1; ++j) {
    int sa = csr_src[j];
    unsigned pa = *(const unsigned*)(xws + (size_t)sa * DIM + lane * 2);
    ax += bf2f((ushort)(pa & 0xffffu));
    ay += bf2f((ushort)(pa >> 16));
  }
  unsigned ps = *(const unsigned*)(xws + (size_t)i * DIM + lane * 2);
  ax += bf2f((ushort)(ps & 0xffffu));
  ay += bf2f((ushort)(ps >> 16));
  float di = dinv[i];
  float2 b = *(const float2*)(bias + lane * 2);
  float vx = di * ax + b.x;
  float vy = di * ay + b.y;
  if (relu) { vx = fmaxf(vx, 0.f); vy = fmaxf(vy, 0.f); }
  *(unsigned*)(outb + (size_t)i * DIM + lane * 2) =
      ((unsigned)f2bf(vy) << 16) | f2bf(vx);
}

// ---------------- readout (bf16 h) ----------------

__global__ __launch_bounds__(128) void readout_kernel(const ushort* __restrict__ h,
                                                      const int* __restrict__ batch,
                                                      unsigned* __restrict__ gmaxk,
                                                      float* __restrict__ gsum) {
  int d = threadIdx.x;
  int start = blockIdx.x * 128;
  if (start >= NNODES) return;
  int end = min(start + 128, NNODES);
  int cur = batch[start];
  float s = 0.f, m = -INFINITY;
  for (int i = start; i < end; ++i) {
    int g = batch[i];
    float v = bf2f(h[(size_t)i * DIM + d]);
    if (g != cur) {
      atomicAdd(&gsum[cur * DIM + d], s);
      atomicMax(&gmaxk[cur * DIM + d], fkey(m));
      cur = g; s = 0.f; m = -INFINITY;
    }
    s += v;
    m = fmaxf(m, v);
  }
  atomicAdd(&gsum[cur * DIM + d], s);
  atomicMax(&gmaxk[cur * DIM + d], fkey(m));
}

__global__ void pack_kernel(const unsigned* __restrict__ gmaxk,
                            const float* __restrict__ gsum, float* __restrict__ out) {
  int idx = blockIdx.x * blockDim.x + threadIdx.x;
  if (idx >= NGRAPHS * 256) return;
  int g = idx >> 8, d = idx & 255;
  float v = (d < 128) ? fdecode(gmaxk[g * DIM + d]) : gsum[g * DIM + (d - 128)];
  out[idx] = rintf(v * 1000.0f) / 1000.0f;
}

// ---------------- launch ----------------

extern "C" void kernel_launch(void* const* d_in, const int* in_sizes, int n_in,
                              void* d_out, int out_size, void* d_ws, size_t ws_size,
                              hipStream_t stream) {
  const int* node_type = (const int*)d_in[0];
  const int* ninv      = (const int*)d_in[1];
  const int* edge      = (const int*)d_in[2];
  const int* batch     = (const int*)d_in[3];
  const float* emb_type = (const float*)d_in[4];
  const float* emb_inv  = (const float*)d_in[5];
  const float* W0 = (const float*)d_in[6];
  const float* B[3] = {(const float*)d_in[7], (const float*)d_in[9], (const float*)d_in[11]};
  const float* W1 = (const float*)d_in[8];
  const float* W2 = (const float*)d_in[10];
  const int* srcp = edge;
  const int* dstp = edge + NEDGES;
  float* out = (float*)d_out;

  char* ws = (char*)d_ws;
  auto alloc = [&](size_t bytes) {
    char* p = ws;
    ws += (bytes + 255) & ~(size_t)255;
    return p;
  };
  ushort* hA     = (ushort*)alloc((size_t)NNODES * DIM * 2);
  ushort* xws    = (ushort*)alloc((size_t)NNODES * DIM * 2);
  float* dinv    = (float*)alloc((size_t)NNODES * 4);
  int* offs      = (int*)alloc((size_t)(NNODES + 1) * 4);
  int* csr_src   = (int*)alloc((size_t)NEDGES * 4);
  unsigned* gbuf = (unsigned*)alloc((size_t)NEDGES * 4);
  unsigned* gmaxk = (unsigned*)alloc((size_t)NGRAPHS * DIM * 4);   // contiguous with
  float* gsum    = (float*)alloc((size_t)NGRAPHS * DIM * 4);       // gsum and bhist
  int* bhist     = (int*)alloc((size_t)NB * 4);
  int* bbase     = (int*)alloc((size_t)(NB + 1) * 4);
  int* blockhist = (int*)alloc((size_t)SC_BLOCKS * NB * 4);
  int* blockbase = (int*)alloc((size_t)SC_BLOCKS * NB * 4);
  float* TW      = (float*)alloc((size_t)7 * DIM * 4);
  ushort* wbf    = (ushort*)alloc((size_t)2 * DIM * DIM * 2);

  // gmaxk | gsum | bhist are contiguous (32 KiB + 32 KiB + NB*4)
  hipMemsetAsync(gmaxk, 0, (size_t)NGRAPHS * DIM * 4 * 2 + NB * 4, stream);

  hist2_kernel<<<SC_BLOCKS, 256, 0, stream>>>(dstp, blockhist, bhist);
  scan2_kernel<<<1, 256, 0, stream>>>(bhist, blockhist, bbase, blockbase, offs);
  scatter2_kernel<<<SC_BLOCKS, 256, 0, stream>>>(srcp, dstp, blockbase, gbuf);
  bucket_sort<<<NB, 256, 0, stream>>>(gbuf, bhist, bbase, csr_src, offs, dinv);

  prep_kernel<<<39, 128, 0, stream>>>(emb_type, emb_inv, W0, W1, W2, TW, wbf);
  xws0_kernel<<<NNODES * 32 / 256, 256, 0, stream>>>(node_type, ninv, TW, dinv, xws);

  for (int l = 0; l < 3; ++l) {
    if (l > 0)
      gemm_kernel<<<256, 256, 0, stream>>>(hA, wbf + (size_t)(l - 1) * DIM * DIM, dinv, xws);
    agg_kernel<<<NNODES / 4, 256, 0, stream>>>(xws, offs, csr_src, dinv, B[l],
                                               hA, l < 2 ? 1 : 0);
  }

  readout_kernel<<<(NNODES + 127) / 128, 128, 0, stream>>>(hA, batch, gmaxk, gsum);
  pack_kernel<<<64, 256, 0, stream>>>(gmaxk, gsum, out);
}

// Round 7
// 328.369 us; speedup vs baseline: 3.9639x; 1.0128x over previous
//
#include <hip/hip_runtime.h>
#include <hip/hip_bf16.h>
#include <cstdint>

#define NNODES 100000
#define NEDGES 1600000
#define NGRAPHS 64
#define DIM 128

#define NB 196          // buckets: dst >> 9 (512 nodes each)
#define BSHIFT 9
#define SC_BLOCKS 200
#define SC_EPB (NEDGES / SC_BLOCKS)        // 8000
#define EB_CAP 10000                       // max edges per bucket (mean 8163)

typedef __attribute__((ext_vector_type(8))) short bf16x8;
typedef __attribute__((ext_vector_type(4))) float f32x4;

__device__ inline ushort f2bf(float f) {
  __hip_bfloat16 h = __float2bfloat16(f);
  return __builtin_bit_cast(ushort, h);
}
__device__ inline float bf2f(ushort u) {
  return __uint_as_float(((unsigned)u) << 16);
}
__device__ inline unsigned fkey(float f) {
  unsigned b = __float_as_uint(f);
  return (b & 0x80000000u) ? ~b : (b | 0x80000000u);
}
__device__ inline float fdecode(unsigned k) {
  unsigned b = (k & 0x80000000u) ? (k & 0x7FFFFFFFu) : ~k;
  return __uint_as_float(b);
}

// ---------------- preprocessing: 2-pass deterministic bucket scatter ----------------
// record = src (17 bits) | local_dst (9 bits) << 17

__global__ __launch_bounds__(256) void hist2_kernel(const int* __restrict__ dst,
                                                    int* __restrict__ blockhist,
                                                    int* __restrict__ bhist) {
  __shared__ int bh[NB];
  int tid = threadIdx.x;
  if (tid < NB) bh[tid] = 0;
  __syncthreads();
  int base = blockIdx.x * SC_EPB;
  for (int o = tid * 4; o < SC_EPB; o += 1024) {
    int4 d4 = *(const int4*)(dst + base + o);
    atomicAdd(&bh[d4.x >> BSHIFT], 1);
    atomicAdd(&bh[d4.y >> BSHIFT], 1);
    atomicAdd(&bh[d4.z >> BSHIFT], 1);
    atomicAdd(&bh[d4.w >> BSHIFT], 1);
  }
  __syncthreads();
  if (tid < NB) {
    blockhist[blockIdx.x * NB + tid] = bh[tid];
    if (bh[tid]) atomicAdd(&bhist[tid], bh[tid]);
  }
}

// 196 blocks: block b computes global bucket base (redundant 196-scan) and
// parallel-scans its own 200-entry blockhist column.
__global__ __launch_bounds__(256) void scanB_kernel(const int* __restrict__ bhist,
                                                    const int* __restrict__ blockhist,
                                                    int* __restrict__ bbase,
                                                    int* __restrict__ blockbase,
                                                    int* __restrict__ offs) {
  __shared__ int gb[256];
  __shared__ int col[256];
  int tid = threadIdx.x;
  int b = blockIdx.x;
  int v = (tid < NB) ? bhist[tid] : 0;
  gb[tid] = v;
  __syncthreads();
  for (int o = 1; o < 256; o <<= 1) {
    int t = (tid >= o) ? gb[tid - o] : 0;
    __syncthreads();
    gb[tid] += t;
    __syncthreads();
  }
  int excl_b = gb[b] - bhist[b];
  int c = (tid < SC_BLOCKS) ? blockhist[tid * NB + b] : 0;
  col[tid] = c;
  __syncthreads();
  for (int o = 1; o < 256; o <<= 1) {
    int t = (tid >= o) ? col[tid - o] : 0;
    __syncthreads();
    col[tid] += t;
    __syncthreads();
  }
  if (tid < SC_BLOCKS) blockbase[tid * NB + b] = excl_b + col[tid] - c;
  if (tid == 0) {
    bbase[b] = excl_b;
    if (b == 0) { bbase[NB] = NEDGES; offs[NNODES] = NEDGES; }
  }
}

__global__ __launch_bounds__(256) void scatter2_kernel(const int* __restrict__ src,
                                                       const int* __restrict__ dst,
                                                       const int* __restrict__ blockbase,
                                                       unsigned* __restrict__ gbuf) {
  __shared__ int lcur[NB];
  int tid = threadIdx.x;
  if (tid < NB) lcur[tid] = blockbase[blockIdx.x * NB + tid];
  __syncthreads();
  int base = blockIdx.x * SC_EPB;
  for (int o = tid * 4; o < SC_EPB; o += 1024) {
    int4 s4 = *(const int4*)(src + base + o);
    int4 d4 = *(const int4*)(dst + base + o);
    int ss[4] = {s4.x, s4.y, s4.z, s4.w};
    int dd[4] = {d4.x, d4.y, d4.z, d4.w};
#pragma unroll
    for (int u = 0; u < 4; ++u) {
      int bk = dd[u] >> BSHIFT;
      unsigned rec = (unsigned)ss[u] | ((unsigned)(dd[u] & 511) << 17);
      int pos = atomicAdd(&lcur[bk], 1);
      gbuf[pos] = rec;
    }
  }
}

// one block per bucket: counting sort by local dst; emits csr_src, offs, dinv
__global__ __launch_bounds__(256) void bucket_sort(const unsigned* __restrict__ gbuf,
                                                   const int* __restrict__ bhist,
                                                   const int* __restrict__ bbase,
                                                   int* __restrict__ csr_src,
                                                   int* __restrict__ offs,
                                                   float* __restrict__ dinv) {
  __shared__ int lhist[512];
  __shared__ int lscan[512];
  __shared__ int lcur2[512];
  __shared__ int lcsr[EB_CAP];
  int tid = threadIdx.x;
  int b = blockIdx.x;
  int ebase = bbase[b];
  int bsize = bhist[b];
  lhist[tid] = 0; lhist[tid + 256] = 0;
  lcur2[tid] = 0; lcur2[tid + 256] = 0;
  __syncthreads();
  for (int k = tid; k < bsize; k += 256)
    atomicAdd(&lhist[(gbuf[ebase + k] >> 17) & 511], 1);
  __syncthreads();
  lscan[tid] = lhist[tid];
  lscan[tid + 256] = lhist[tid + 256];
  __syncthreads();
  for (int o = 1; o < 256; o <<= 1) {
    int a = (tid >= o) ? lscan[tid - o] : 0;
    int c = (tid >= o) ? lscan[256 + tid - o] : 0;
    __syncthreads();
    lscan[tid] += a;
    lscan[256 + tid] += c;
    __syncthreads();
  }
  int tot = lscan[255];
  __syncthreads();
  lscan[256 + tid] += tot;
  __syncthreads();
  int nodebase = b << BSHIFT;
#pragma unroll
  for (int hh = 0; hh < 2; ++hh) {
    int l = hh * 256 + tid;
    int i = nodebase + l;
    if (i < NNODES) {
      int c = lhist[l];
      offs[i] = ebase + (lscan[l] - c);
      dinv[i] = rsqrtf((float)c + 1.0f);
    }
  }
  for (int k = tid; k < bsize; k += 256) {
    unsigned e = gbuf[ebase + k];
    int l = (e >> 17) & 511;
    int p = atomicAdd(&lcur2[l], 1);
    int pos = (lscan[l] - lhist[l]) + p;
    if (pos < EB_CAP) lcsr[pos] = (int)(e & 0x1FFFFu);
  }
  __syncthreads();
  for (int k = tid; k < bsize; k += 256) csr_src[ebase + k] = lcsr[k];
}

// ---------------- fused prep: TW = [emb_type;emb_inv]@W0 (f32) + W1/W2 -> bf16 ----------------

__global__ __launch_bounds__(128) void prep_kernel(const float* __restrict__ et,
                                                   const float* __restrict__ ei,
                                                   const float* __restrict__ W0,
                                                   const float* __restrict__ W1,
                                                   const float* __restrict__ W2,
                                                   float* __restrict__ TW,
                                                   ushort* __restrict__ wbf) {
  int b = blockIdx.x;
  int tid = threadIdx.x;
  if (b < 7) {
    const float* in = (b < 4) ? (et + b * DIM) : (ei + (b - 4) * DIM);
    float acc = 0.f;
    for (int k = 0; k < DIM; ++k) acc += in[k] * W0[k * DIM + tid];
    TW[b * DIM + tid] = acc;
  } else {
    int m = (b - 7) >> 4;               // 0: W1, 1: W2
    int blk = (b - 7) & 15;
    const float* w = m ? W2 : W1;
    ushort* o = wbf + (size_t)m * DIM * DIM;
    int base = blk * 1024 + tid * 8;
    float4 a = *(const float4*)(w + base);
    float4 c = *(const float4*)(w + base + 4);
    uint4 r;
    r.x = ((unsigned)f2bf(a.y) << 16) | f2bf(a.x);
    r.y = ((unsigned)f2bf(a.w) << 16) | f2bf(a.z);
    r.z = ((unsigned)f2bf(c.y) << 16) | f2bf(c.x);
    r.w = ((unsigned)f2bf(c.w) << 16) | f2bf(c.z);
    *(uint4*)(o + base) = r;
  }
}

// xws0[i] = dinv[i] * (TW[nt[i]] + TW[4+ninv[i]])  -> bf16
__global__ void xws0_kernel(const int* __restrict__ nt, const int* __restrict__ ninv,
                            const float* __restrict__ TW, const float* __restrict__ dinv,
                            ushort* __restrict__ xws) {
  int idx = blockIdx.x * blockDim.x + threadIdx.x;
  if (idx >= NNODES * 32) return;
  int i = idx >> 5, d4 = (idx & 31) << 2;
  float4 a = *(const float4*)(TW + nt[i] * DIM + d4);
  float4 b = *(const float4*)(TW + (4 + ninv[i]) * DIM + d4);
  float di = dinv[i];
  uint2 o;
  o.x = ((unsigned)f2bf((a.y + b.y) * di) << 16) | f2bf((a.x + b.x) * di);
  o.y = ((unsigned)f2bf((a.w + b.w) * di) << 16) | f2bf((a.z + b.z) * di);
  *(uint2*)(xws + (size_t)i * DIM + d4) = o;
}

// ---------------- MFMA GEMM: xws = dinv * (h @ W) ----------------

__global__ __launch_bounds__(256) void gemm_kernel(const ushort* __restrict__ h,
                                                   const ushort* __restrict__ wb,
                                                   const float* __restrict__ dinv,
                                                   ushort* __restrict__ out) {
  __shared__ ushort Ws[32 * 64 * 8];  // B-fragment order
  int tid = threadIdx.x;
  for (int g = tid; g < 2048; g += 256) {
    int kt = g >> 6, l = g & 63;
    int ks = kt >> 3, t = kt & 7;
    int kb = ks * 32 + ((l >> 4) << 3);
    int col = t * 16 + (l & 15);
#pragma unroll
    for (int j = 0; j < 8; ++j) Ws[g * 8 + j] = wb[(kb + j) * DIM + col];
  }
  __syncthreads();
  int w = tid >> 6, lane = tid & 63;
  for (int tile = blockIdx.x * 4 + w; tile < NNODES / 16; tile += gridDim.x * 4) {
    int row0 = tile * 16;
    const ushort* hrow = h + (size_t)(row0 + (lane & 15)) * DIM + ((lane >> 4) << 3);
    f32x4 acc[8];
#pragma unroll
    for (int t = 0; t < 8; ++t) acc[t] = {0.f, 0.f, 0.f, 0.f};
#pragma unroll
    for (int ks = 0; ks < 4; ++ks) {
      bf16x8 a = *(const bf16x8*)(hrow + ks * 32);
#pragma unroll
      for (int t = 0; t < 8; ++t) {
        bf16x8 b = *(const bf16x8*)&Ws[((ks * 8 + t) * 64 + lane) * 8];
        acc[t] = __builtin_amdgcn_mfma_f32_16x16x32_bf16(a, b, acc[t], 0, 0, 0);
      }
    }
    int rbase = row0 + ((lane >> 4) << 2);
    int cbase = lane & 15;
    float4 dv = *(const float4*)(dinv + rbase);
    float dvr[4] = {dv.x, dv.y, dv.z, dv.w};
#pragma unroll
    for (int t = 0; t < 8; ++t)
#pragma unroll
      for (int r = 0; r < 4; ++r)
        out[(size_t)(rbase + r) * DIM + t * 16 + cbase] = f2bf(acc[t][r] * dvr[r]);
  }
}

// ---------------- aggregation: one wave per node, 16-deep gather ----------------

__global__ __launch_bounds__(256, 8) void agg_kernel(const ushort* __restrict__ xws,
                                                     const int* __restrict__ offs,
                                                     const int* __restrict__ csr_src,
                                                     const float* __restrict__ dinv,
                                                     const float* __restrict__ bias,
                                                     ushort* __restrict__ outb, int relu) {
  int i = blockIdx.x * 4 + (threadIdx.x >> 6);
  if (i >= NNODES) return;
  int lane = threadIdx.x & 63;
  int s0 = offs[i], s1 = offs[i + 1];
  float ax = 0.f, ay = 0.f;
  int j = s0;
  for (; j + 16 <= s1; j += 16) {
    int s[16];
#pragma unroll
    for (int u = 0; u < 16; ++u) s[u] = csr_src[j + u];
    unsigned p[16];
#pragma unroll
    for (int u = 0; u < 16; ++u)
      p[u] = *(const unsigned*)(xws + (size_t)s[u] * DIM + lane * 2);
#pragma unroll
    for (int u = 0; u < 16; ++u) {
      ax += bf2f((ushort)(p[u] & 0xffffu));
      ay += bf2f((ushort)(p[u] >> 16));
    }
  }
  for (; j + 4 <= s1; j += 4) {
    int s[4];
#pragma unroll
    for (int u = 0; u < 4; ++u) s[u] = csr_src[j + u];
    unsigned p[4];
#pragma unroll
    for (int u = 0; u < 4; ++u)
      p[u] = *(const unsigned*)(xws + (size_t)s[u] * DIM + lane * 2);
#pragma unroll
    for (int u = 0; u < 4; ++u) {
      ax += bf2f((ushort)(p[u] & 0xffffu));
      ay += bf2f((ushort)(p[u] >> 16));
    }
  }
  for (; j < s1; ++j) {
    int sa = csr_src[j];
    unsigned pa = *(const unsigned*)(xws + (size_t)sa * DIM + lane * 2);
    ax += bf2f((ushort)(pa & 0xffffu));
    ay += bf2f((ushort)(pa >> 16));
  }
  unsigned ps = *(const unsigned*)(xws + (size_t)i * DIM + lane * 2);
  ax += bf2f((ushort)(ps & 0xffffu));
  ay += bf2f((ushort)(ps >> 16));
  float di = dinv[i];
  float2 b = *(const float2*)(bias + lane * 2);
  float vx = di * ax + b.x;
  float vy = di * ay + b.y;
  if (relu) { vx = fmaxf(vx, 0.f); vy = fmaxf(vy, 0.f); }
  *(unsigned*)(outb + (size_t)i * DIM + lane * 2) =
      ((unsigned)f2bf(vy) << 16) | f2bf(vx);
}

// ---------------- readout (bf16 h) ----------------

__global__ __launch_bounds__(128) void readout_kernel(const ushort* __restrict__ h,
                                                      const int* __restrict__ batch,
                                                      unsigned* __restrict__ gmaxk,
                                                      float* __restrict__ gsum) {
  int d = threadIdx.x;
  int start = blockIdx.x * 128;
  if (start >= NNODES) return;
  int end = min(start + 128, NNODES);
  int cur = batch[start];
  float s = 0.f, m = -INFINITY;
  for (int i = start; i < end; ++i) {
    int g = batch[i];
    float v = bf2f(h[(size_t)i * DIM + d]);
    if (g != cur) {
      atomicAdd(&gsum[cur * DIM + d], s);
      atomicMax(&gmaxk[cur * DIM + d], fkey(m));
      cur = g; s = 0.f; m = -INFINITY;
    }
    s += v;
    m = fmaxf(m, v);
  }
  atomicAdd(&gsum[cur * DIM + d], s);
  atomicMax(&gmaxk[cur * DIM + d], fkey(m));
}

__global__ void pack_kernel(const unsigned* __restrict__ gmaxk,
                            const float* __restrict__ gsum, float* __restrict__ out) {
  int idx = blockIdx.x * blockDim.x + threadIdx.x;
  if (idx >= NGRAPHS * 256) return;
  int g = idx >> 8, d = idx & 255;
  float v = (d < 128) ? fdecode(gmaxk[g * DIM + d]) : gsum[g * DIM + (d - 128)];
  out[idx] = rintf(v * 1000.0f) / 1000.0f;
}

// ---------------- launch ----------------

extern "C" void kernel_launch(void* const* d_in, const int* in_sizes, int n_in,
                              void* d_out, int out_size, void* d_ws, size_t ws_size,
                              hipStream_t stream) {
  const int* node_type = (const int*)d_in[0];
  const int* ninv      = (const int*)d_in[1];
  const int* edge      = (const int*)d_in[2];
  const int* batch     = (const int*)d_in[3];
  const float* emb_type = (const float*)d_in[4];
  const float* emb_inv  = (const float*)d_in[5];
  const float* W0 = (const float*)d_in[6];
  const float* B[3] = {(const float*)d_in[7], (const float*)d_in[9], (const float*)d_in[11]};
  const float* W1 = (const float*)d_in[8];
  const float* W2 = (const float*)d_in[10];
  const int* srcp = edge;
  const int* dstp = edge + NEDGES;
  float* out = (float*)d_out;

  char* ws = (char*)d_ws;
  auto alloc = [&](size_t bytes) {
    char* p = ws;
    ws += (bytes + 255) & ~(size_t)255;
    return p;
  };
  ushort* hA     = (ushort*)alloc((size_t)NNODES * DIM * 2);
  ushort* xws    = (ushort*)alloc((size_t)NNODES * DIM * 2);
  float* dinv    = (float*)alloc((size_t)NNODES * 4);
  int* offs      = (int*)alloc((size_t)(NNODES + 1) * 4);
  int* csr_src   = (int*)alloc((size_t)NEDGES * 4);
  unsigned* gbuf = (unsigned*)alloc((size_t)NEDGES * 4);
  unsigned* gmaxk = (unsigned*)alloc((size_t)NGRAPHS * DIM * 4);   // contiguous with
  float* gsum    = (float*)alloc((size_t)NGRAPHS * DIM * 4);       // gsum and bhist
  int* bhist     = (int*)alloc((size_t)NB * 4);
  int* bbase     = (int*)alloc((size_t)(NB + 1) * 4);
  int* blockhist = (int*)alloc((size_t)SC_BLOCKS * NB * 4);
  int* blockbase = (int*)alloc((size_t)SC_BLOCKS * NB * 4);
  float* TW      = (float*)alloc((size_t)7 * DIM * 4);
  ushort* wbf    = (ushort*)alloc((size_t)2 * DIM * DIM * 2);

  // gmaxk | gsum | bhist are contiguous (32 KiB + 32 KiB + NB*4)
  hipMemsetAsync(gmaxk, 0, (size_t)NGRAPHS * DIM * 4 * 2 + NB * 4, stream);

  hist2_kernel<<<SC_BLOCKS, 256, 0, stream>>>(dstp, blockhist, bhist);
  scanB_kernel<<<NB, 256, 0, stream>>>(bhist, blockhist, bbase, blockbase, offs);
  scatter2_kernel<<<SC_BLOCKS, 256, 0, stream>>>(srcp, dstp, blockbase, gbuf);
  bucket_sort<<<NB, 256, 0, stream>>>(gbuf, bhist, bbase, csr_src, offs, dinv);

  prep_kernel<<<39, 128, 0, stream>>>(emb_type, emb_inv, W0, W1, W2, TW, wbf);
  xws0_kernel<<<NNODES * 32 / 256, 256, 0, stream>>>(node_type, ninv, TW, dinv, xws);

  for (int l = 0; l < 3; ++l) {
    if (l > 0)
      gemm_kernel<<<1024, 256, 0, stream>>>(hA, wbf + (size_t)(l - 1) * DIM * DIM, dinv, xws);
    agg_kernel<<<NNODES / 4, 256, 0, stream>>>(xws, offs, csr_src, dinv, B[l],
                                               hA, l < 2 ? 1 : 0);
  }

  readout_kernel<<<(NNODES + 127) / 128, 128, 0, stream>>>(hA, batch, gmaxk, gsum);
  pack_kernel<<<64, 256, 0, stream>>>(gmaxk, gsum, out);
}

// Round 8
// 295.373 us; speedup vs baseline: 4.4068x; 1.1117x over previous
//
#include <hip/hip_runtime.h>
#include <hip/hip_bf16.h>
#include <cstdint>

#define NNODES 100000
#define NEDGES 1600000
#define NGRAPHS 64
#define DIM 128

#define NB 196          // buckets: dst >> 9 (512 nodes each)
#define BSHIFT 9
#define SC_BLOCKS 200
#define SC_EPB (NEDGES / SC_BLOCKS)        // 8000
#define EB_CAP 10000                       // max edges per bucket (mean 8163)

typedef __attribute__((ext_vector_type(8))) short bf16x8;
typedef __attribute__((ext_vector_type(4))) float f32x4;

__device__ inline ushort f2bf(float f) {
  __hip_bfloat16 h = __float2bfloat16(f);
  return __builtin_bit_cast(ushort, h);
}
__device__ inline float bf2f(ushort u) {
  return __uint_as_float(((unsigned)u) << 16);
}
__device__ inline unsigned fkey(float f) {
  unsigned b = __float_as_uint(f);
  return (b & 0x80000000u) ? ~b : (b | 0x80000000u);
}
__device__ inline float fdecode(unsigned k) {
  unsigned b = (k & 0x80000000u) ? (k & 0x7FFFFFFFu) : ~k;
  return __uint_as_float(b);
}

// ---------------- preprocessing: 2-pass deterministic bucket scatter ----------------
// record = src (17 bits) | local_dst (9 bits) << 17

__global__ __launch_bounds__(256) void hist2_kernel(const int* __restrict__ dst,
                                                    int* __restrict__ blockhist,
                                                    int* __restrict__ bhist) {
  __shared__ int bh[NB];
  int tid = threadIdx.x;
  if (tid < NB) bh[tid] = 0;
  __syncthreads();
  int base = blockIdx.x * SC_EPB;
  for (int o = tid * 4; o < SC_EPB; o += 1024) {
    int4 d4 = *(const int4*)(dst + base + o);
    atomicAdd(&bh[d4.x >> BSHIFT], 1);
    atomicAdd(&bh[d4.y >> BSHIFT], 1);
    atomicAdd(&bh[d4.z >> BSHIFT], 1);
    atomicAdd(&bh[d4.w >> BSHIFT], 1);
  }
  __syncthreads();
  if (tid < NB) {
    blockhist[blockIdx.x * NB + tid] = bh[tid];
    if (bh[tid]) atomicAdd(&bhist[tid], bh[tid]);
  }
}

// 196 blocks: block b computes global bucket base (redundant 196-scan) and
// parallel-scans its own 200-entry blockhist column.
__global__ __launch_bounds__(256) void scanB_kernel(const int* __restrict__ bhist,
                                                    const int* __restrict__ blockhist,
                                                    int* __restrict__ bbase,
                                                    int* __restrict__ blockbase,
                                                    int* __restrict__ offs) {
  __shared__ int gb[256];
  __shared__ int col[256];
  int tid = threadIdx.x;
  int b = blockIdx.x;
  int v = (tid < NB) ? bhist[tid] : 0;
  gb[tid] = v;
  __syncthreads();
  for (int o = 1; o < 256; o <<= 1) {
    int t = (tid >= o) ? gb[tid - o] : 0;
    __syncthreads();
    gb[tid] += t;
    __syncthreads();
  }
  int excl_b = gb[b] - bhist[b];
  int c = (tid < SC_BLOCKS) ? blockhist[tid * NB + b] : 0;
  col[tid] = c;
  __syncthreads();
  for (int o = 1; o < 256; o <<= 1) {
    int t = (tid >= o) ? col[tid - o] : 0;
    __syncthreads();
    col[tid] += t;
    __syncthreads();
  }
  if (tid < SC_BLOCKS) blockbase[tid * NB + b] = excl_b + col[tid] - c;
  if (tid == 0) {
    bbase[b] = excl_b;
    if (b == 0) { bbase[NB] = NEDGES; offs[NNODES] = NEDGES; }
  }
}

__global__ __launch_bounds__(256) void scatter2_kernel(const int* __restrict__ src,
                                                       const int* __restrict__ dst,
                                                       const int* __restrict__ blockbase,
                                                       unsigned* __restrict__ gbuf) {
  __shared__ int lcur[NB];
  int tid = threadIdx.x;
  if (tid < NB) lcur[tid] = blockbase[blockIdx.x * NB + tid];
  __syncthreads();
  int base = blockIdx.x * SC_EPB;
  for (int o = tid * 4; o < SC_EPB; o += 1024) {
    int4 s4 = *(const int4*)(src + base + o);
    int4 d4 = *(const int4*)(dst + base + o);
    int ss[4] = {s4.x, s4.y, s4.z, s4.w};
    int dd[4] = {d4.x, d4.y, d4.z, d4.w};
#pragma unroll
    for (int u = 0; u < 4; ++u) {
      int bk = dd[u] >> BSHIFT;
      unsigned rec = (unsigned)ss[u] | ((unsigned)(dd[u] & 511) << 17);
      int pos = atomicAdd(&lcur[bk], 1);
      gbuf[pos] = rec;
    }
  }
}

// one block per bucket: counting sort by local dst; emits csr_src, offs, dinv
__global__ __launch_bounds__(256) void bucket_sort(const unsigned* __restrict__ gbuf,
                                                   const int* __restrict__ bhist,
                                                   const int* __restrict__ bbase,
                                                   int* __restrict__ csr_src,
                                                   int* __restrict__ offs,
                                                   float* __restrict__ dinv) {
  __shared__ int lhist[512];
  __shared__ int lscan[512];
  __shared__ int lcur2[512];
  __shared__ int lcsr[EB_CAP];
  int tid = threadIdx.x;
  int b = blockIdx.x;
  int ebase = bbase[b];
  int bsize = bhist[b];
  lhist[tid] = 0; lhist[tid + 256] = 0;
  lcur2[tid] = 0; lcur2[tid + 256] = 0;
  __syncthreads();
  for (int k = tid; k < bsize; k += 256)
    atomicAdd(&lhist[(gbuf[ebase + k] >> 17) & 511], 1);
  __syncthreads();
  lscan[tid] = lhist[tid];
  lscan[tid + 256] = lhist[tid + 256];
  __syncthreads();
  for (int o = 1; o < 256; o <<= 1) {
    int a = (tid >= o) ? lscan[tid - o] : 0;
    int c = (tid >= o) ? lscan[256 + tid - o] : 0;
    __syncthreads();
    lscan[tid] += a;
    lscan[256 + tid] += c;
    __syncthreads();
  }
  int tot = lscan[255];
  __syncthreads();
  lscan[256 + tid] += tot;
  __syncthreads();
  int nodebase = b << BSHIFT;
#pragma unroll
  for (int hh = 0; hh < 2; ++hh) {
    int l = hh * 256 + tid;
    int i = nodebase + l;
    if (i < NNODES) {
      int c = lhist[l];
      offs[i] = ebase + (lscan[l] - c);
      dinv[i] = rsqrtf((float)c + 1.0f);
    }
  }
  for (int k = tid; k < bsize; k += 256) {
    unsigned e = gbuf[ebase + k];
    int l = (e >> 17) & 511;
    int p = atomicAdd(&lcur2[l], 1);
    int pos = (lscan[l] - lhist[l]) + p;
    if (pos < EB_CAP) lcsr[pos] = (int)(e & 0x1FFFFu);
  }
  __syncthreads();
  for (int k = tid; k < bsize; k += 256) csr_src[ebase + k] = lcsr[k];
}

// ---------------- fused prep: TW = [emb_type;emb_inv]@W0 (f32) + W1/W2 -> bf16 ----------------

__global__ __launch_bounds__(128) void prep_kernel(const float* __restrict__ et,
                                                   const float* __restrict__ ei,
                                                   const float* __restrict__ W0,
                                                   const float* __restrict__ W1,
                                                   const float* __restrict__ W2,
                                                   float* __restrict__ TW,
                                                   ushort* __restrict__ wbf) {
  int b = blockIdx.x;
  int tid = threadIdx.x;
  if (b < 7) {
    const float* in = (b < 4) ? (et + b * DIM) : (ei + (b - 4) * DIM);
    float acc = 0.f;
    for (int k = 0; k < DIM; ++k) acc += in[k] * W0[k * DIM + tid];
    TW[b * DIM + tid] = acc;
  } else {
    int m = (b - 7) >> 4;               // 0: W1, 1: W2
    int blk = (b - 7) & 15;
    const float* w = m ? W2 : W1;
    ushort* o = wbf + (size_t)m * DIM * DIM;
    int base = blk * 1024 + tid * 8;
    float4 a = *(const float4*)(w + base);
    float4 c = *(const float4*)(w + base + 4);
    uint4 r;
    r.x = ((unsigned)f2bf(a.y) << 16) | f2bf(a.x);
    r.y = ((unsigned)f2bf(a.w) << 16) | f2bf(a.z);
    r.z = ((unsigned)f2bf(c.y) << 16) | f2bf(c.x);
    r.w = ((unsigned)f2bf(c.w) << 16) | f2bf(c.z);
    *(uint4*)(o + base) = r;
  }
}

// ---------------- layer 0 via dictionary coefficients ----------------
// C_i[k] = sum_{j in N(i) U {i}} dinv_j * [dict_k(j)],  k: 0..3 = nt, 4..6 = ninv

__global__ __launch_bounds__(256) void coef_kernel(const int* __restrict__ offs,
                                                   const int* __restrict__ csr_src,
                                                   const int* __restrict__ nt,
                                                   const int* __restrict__ nv,
                                                   const float* __restrict__ dinv,
                                                   float* __restrict__ Cbuf) {
  int gid = blockIdx.x * 256 + threadIdx.x;
  int i = gid >> 2;
  int sl = gid & 3;
  if (i >= NNODES) return;
  int s0 = offs[i], s1 = offs[i + 1];
  float c0 = 0.f, c1 = 0.f, c2 = 0.f, c3 = 0.f, c4 = 0.f, c5 = 0.f, c6 = 0.f;
  for (int j = s0 + sl; j < s1; j += 4) {
    int s = csr_src[j];
    float dv = dinv[s];
    int t = nt[s], v = nv[s];
    c0 += (t == 0) ? dv : 0.f;
    c1 += (t == 1) ? dv : 0.f;
    c2 += (t == 2) ? dv : 0.f;
    c3 += (t == 3) ? dv : 0.f;
    c4 += (v == 0) ? dv : 0.f;
    c5 += (v == 1) ? dv : 0.f;
    c6 += (v == 2) ? dv : 0.f;
  }
#pragma unroll
  for (int o = 1; o < 4; o <<= 1) {
    c0 += __shfl_xor(c0, o);
    c1 += __shfl_xor(c1, o);
    c2 += __shfl_xor(c2, o);
    c3 += __shfl_xor(c3, o);
    c4 += __shfl_xor(c4, o);
    c5 += __shfl_xor(c5, o);
    c6 += __shfl_xor(c6, o);
  }
  if (sl == 0) {
    float di = dinv[i];
    int t = nt[i], v = nv[i];
    c0 += (t == 0) ? di : 0.f;
    c1 += (t == 1) ? di : 0.f;
    c2 += (t == 2) ? di : 0.f;
    c3 += (t == 3) ? di : 0.f;
    c4 += (v == 0) ? di : 0.f;
    c5 += (v == 1) ? di : 0.f;
    c6 += (v == 2) ? di : 0.f;
    float4 lo = {c0, c1, c2, c3};
    float4 hi = {c4, c5, c6, 0.f};
    *(float4*)(Cbuf + (size_t)i * 8) = lo;
    *(float4*)(Cbuf + (size_t)i * 8 + 4) = hi;
  }
}

// h1[i][d] = relu(dinv_i * (C_i @ TW)[d] + b0[d])  -> bf16
__global__ void h1_kernel(const float* __restrict__ Cbuf, const float* __restrict__ TW,
                          const float* __restrict__ dinv, const float* __restrict__ b0,
                          ushort* __restrict__ h) {
  int idx = blockIdx.x * blockDim.x + threadIdx.x;
  if (idx >= NNODES * 32) return;
  int i = idx >> 5, d4 = (idx & 31) << 2;
  const float* C = Cbuf + (size_t)i * 8;
  float4 acc = {0.f, 0.f, 0.f, 0.f};
#pragma unroll
  for (int k = 0; k < 7; ++k) {
    float ck = C[k];
    float4 tw = *(const float4*)(TW + k * DIM + d4);
    acc.x += ck * tw.x; acc.y += ck * tw.y;
    acc.z += ck * tw.z; acc.w += ck * tw.w;
  }
  float di = dinv[i];
  float4 bb = *(const float4*)(b0 + d4);
  float vx = fmaxf(di * acc.x + bb.x, 0.f);
  float vy = fmaxf(di * acc.y + bb.y, 0.f);
  float vz = fmaxf(di * acc.z + bb.z, 0.f);
  float vw = fmaxf(di * acc.w + bb.w, 0.f);
  uint2 o;
  o.x = ((unsigned)f2bf(vy) << 16) | f2bf(vx);
  o.y = ((unsigned)f2bf(vw) << 16) | f2bf(vz);
  *(uint2*)(h + (size_t)i * DIM + d4) = o;
}

// ---------------- MFMA GEMM: xws = dinv * (h @ W) ----------------

__global__ __launch_bounds__(256) void gemm_kernel(const ushort* __restrict__ h,
                                                   const ushort* __restrict__ wb,
                                                   const float* __restrict__ dinv,
                                                   ushort* __restrict__ out) {
  __shared__ ushort Ws[32 * 64 * 8];  // B-fragment order
  int tid = threadIdx.x;
  for (int g = tid; g < 2048; g += 256) {
    int kt = g >> 6, l = g & 63;
    int ks = kt >> 3, t = kt & 7;
    int kb = ks * 32 + ((l >> 4) << 3);
    int col = t * 16 + (l & 15);
#pragma unroll
    for (int j = 0; j < 8; ++j) Ws[g * 8 + j] = wb[(kb + j) * DIM + col];
  }
  __syncthreads();
  int w = tid >> 6, lane = tid & 63;
  for (int tile = blockIdx.x * 4 + w; tile < NNODES / 16; tile += gridDim.x * 4) {
    int row0 = tile * 16;
    const ushort* hrow = h + (size_t)(row0 + (lane & 15)) * DIM + ((lane >> 4) << 3);
    f32x4 acc[8];
#pragma unroll
    for (int t = 0; t < 8; ++t) acc[t] = {0.f, 0.f, 0.f, 0.f};
#pragma unroll
    for (int ks = 0; ks < 4; ++ks) {
      bf16x8 a = *(const bf16x8*)(hrow + ks * 32);
#pragma unroll
      for (int t = 0; t < 8; ++t) {
        bf16x8 b = *(const bf16x8*)&Ws[((ks * 8 + t) * 64 + lane) * 8];
        acc[t] = __builtin_amdgcn_mfma_f32_16x16x32_bf16(a, b, acc[t], 0, 0, 0);
      }
    }
    int rbase = row0 + ((lane >> 4) << 2);
    int cbase = lane & 15;
    float4 dv = *(const float4*)(dinv + rbase);
    float dvr[4] = {dv.x, dv.y, dv.z, dv.w};
#pragma unroll
    for (int t = 0; t < 8; ++t)
#pragma unroll
      for (int r = 0; r < 4; ++r)
        out[(size_t)(rbase + r) * DIM + t * 16 + cbase] = f2bf(acc[t][r] * dvr[r]);
  }
}

// ---------------- aggregation: one wave per node, 16-deep gather ----------------

__global__ __launch_bounds__(256, 8) void agg_kernel(const ushort* __restrict__ xws,
                                                     const int* __restrict__ offs,
                                                     const int* __restrict__ csr_src,
                                                     const float* __restrict__ dinv,
                                                     const float* __restrict__ bias,
                                                     ushort* __restrict__ outb, int relu) {
  int i = blockIdx.x * 4 + (threadIdx.x >> 6);
  if (i >= NNODES) return;
  int lane = threadIdx.x & 63;
  int s0 = offs[i], s1 = offs[i + 1];
  float ax = 0.f, ay = 0.f;
  int j = s0;
  for (; j + 16 <= s1; j += 16) {
    int s[16];
#pragma unroll
    for (int u = 0; u < 16; ++u) s[u] = csr_src[j + u];
    unsigned p[16];
#pragma unroll
    for (int u = 0; u < 16; ++u)
      p[u] = *(const unsigned*)(xws + (size_t)s[u] * DIM + lane * 2);
#pragma unroll
    for (int u = 0; u < 16; ++u) {
      ax += bf2f((ushort)(p[u] & 0xffffu));
      ay += bf2f((ushort)(p[u] >> 16));
    }
  }
  for (; j + 4 <= s1; j += 4) {
    int s[4];
#pragma unroll
    for (int u = 0; u < 4; ++u) s[u] = csr_src[j + u];
    unsigned p[4];
#pragma unroll
    for (int u = 0; u < 4; ++u)
      p[u] = *(const unsigned*)(xws + (size_t)s[u] * DIM + lane * 2);
#pragma unroll
    for (int u = 0; u < 4; ++u) {
      ax += bf2f((ushort)(p[u] & 0xffffu));
      ay += bf2f((ushort)(p[u] >> 16));
    }
  }
  for (; j < s1; ++j) {
    int sa = csr_src[j];
    unsigned pa = *(const unsigned*)(xws + (size_t)sa * DIM + lane * 2);
    ax += bf2f((ushort)(pa & 0xffffu));
    ay += bf2f((ushort)(pa >> 16));
  }
  unsigned ps = *(const unsigned*)(xws + (size_t)i * DIM + lane * 2);
  ax += bf2f((ushort)(ps & 0xffffu));
  ay += bf2f((ushort)(ps >> 16));
  float di = dinv[i];
  float2 b = *(const float2*)(bias + lane * 2);
  float vx = di * ax + b.x;
  float vy = di * ay + b.y;
  if (relu) { vx = fmaxf(vx, 0.f); vy = fmaxf(vy, 0.f); }
  *(unsigned*)(outb + (size_t)i * DIM + lane * 2) =
      ((unsigned)f2bf(vy) << 16) | f2bf(vx);
}

// ---------------- readout (bf16 h) ----------------

__global__ __launch_bounds__(128) void readout_kernel(const ushort* __restrict__ h,
                                                      const int* __restrict__ batch,
                                                      unsigned* __restrict__ gmaxk,
                                                      float* __restrict__ gsum) {
  int d = threadIdx.x;
  int start = blockIdx.x * 128;
  if (start >= NNODES) return;
  int end = min(start + 128, NNODES);
  int cur = batch[start];
  float s = 0.f, m = -INFINITY;
  for (int i = start; i < end; ++i) {
    int g = batch[i];
    float v = bf2f(h[(size_t)i * DIM + d]);
    if (g != cur) {
      atomicAdd(&gsum[cur * DIM + d], s);
      atomicMax(&gmaxk[cur * DIM + d], fkey(m));
      cur = g; s = 0.f; m = -INFINITY;
    }
    s += v;
    m = fmaxf(m, v);
  }
  atomicAdd(&gsum[cur * DIM + d], s);
  atomicMax(&gmaxk[cur * DIM + d], fkey(m));
}

__global__ void pack_kernel(const unsigned* __restrict__ gmaxk,
                            const float* __restrict__ gsum, float* __restrict__ out) {
  int idx = blockIdx.x * blockDim.x + threadIdx.x;
  if (idx >= NGRAPHS * 256) return;
  int g = idx >> 8, d = idx & 255;
  float v = (d < 128) ? fdecode(gmaxk[g * DIM + d]) : gsum[g * DIM + (d - 128)];
  out[idx] = rintf(v * 1000.0f) / 1000.0f;
}

// ---------------- launch ----------------

extern "C" void kernel_launch(void* const* d_in, const int* in_sizes, int n_in,
                              void* d_out, int out_size, void* d_ws, size_t ws_size,
                              hipStream_t stream) {
  const int* node_type = (const int*)d_in[0];
  const int* ninv      = (const int*)d_in[1];
  const int* edge      = (const int*)d_in[2];
  const int* batch     = (const int*)d_in[3];
  const float* emb_type = (const float*)d_in[4];
  const float* emb_inv  = (const float*)d_in[5];
  const float* W0 = (const float*)d_in[6];
  const float* B[3] = {(const float*)d_in[7], (const float*)d_in[9], (const float*)d_in[11]};
  const float* W1 = (const float*)d_in[8];
  const float* W2 = (const float*)d_in[10];
  const int* srcp = edge;
  const int* dstp = edge + NEDGES;
  float* out = (float*)d_out;

  char* ws = (char*)d_ws;
  auto alloc = [&](size_t bytes) {
    char* p = ws;
    ws += (bytes + 255) & ~(size_t)255;
    return p;
  };
  ushort* hA     = (ushort*)alloc((size_t)NNODES * DIM * 2);
  ushort* xws    = (ushort*)alloc((size_t)NNODES * DIM * 2);
  float* dinv    = (float*)alloc((size_t)NNODES * 4);
  int* offs      = (int*)alloc((size_t)(NNODES + 1) * 4);
  int* csr_src   = (int*)alloc((size_t)NEDGES * 4);
  unsigned* gbuf = (unsigned*)alloc((size_t)NEDGES * 4);
  float* Cbuf    = (float*)alloc((size_t)NNODES * 8 * 4);
  unsigned* gmaxk = (unsigned*)alloc((size_t)NGRAPHS * DIM * 4);   // contiguous with
  float* gsum    = (float*)alloc((size_t)NGRAPHS * DIM * 4);       // gsum and bhist
  int* bhist     = (int*)alloc((size_t)NB * 4);
  int* bbase     = (int*)alloc((size_t)(NB + 1) * 4);
  int* blockhist = (int*)alloc((size_t)SC_BLOCKS * NB * 4);
  int* blockbase = (int*)alloc((size_t)SC_BLOCKS * NB * 4);
  float* TW      = (float*)alloc((size_t)7 * DIM * 4);
  ushort* wbf    = (ushort*)alloc((size_t)2 * DIM * DIM * 2);

  // gmaxk | gsum | bhist are contiguous (32 KiB + 32 KiB + NB*4)
  hipMemsetAsync(gmaxk, 0, (size_t)NGRAPHS * DIM * 4 * 2 + NB * 4, stream);

  hist2_kernel<<<SC_BLOCKS, 256, 0, stream>>>(dstp, blockhist, bhist);
  scanB_kernel<<<NB, 256, 0, stream>>>(bhist, blockhist, bbase, blockbase, offs);
  scatter2_kernel<<<SC_BLOCKS, 256, 0, stream>>>(srcp, dstp, blockbase, gbuf);
  bucket_sort<<<NB, 256, 0, stream>>>(gbuf, bhist, bbase, csr_src, offs, dinv);

  prep_kernel<<<39, 128, 0, stream>>>(emb_type, emb_inv, W0, W1, W2, TW, wbf);
  coef_kernel<<<(NNODES * 4 + 255) / 256, 256, 0, stream>>>(offs, csr_src, node_type,
                                                            ninv, dinv, Cbuf);
  h1_kernel<<<NNODES * 32 / 256, 256, 0, stream>>>(Cbuf, TW, dinv, B[0], hA);

  for (int l = 1; l < 3; ++l) {
    gemm_kernel<<<1024, 256, 0, stream>>>(hA, wbf + (size_t)(l - 1) * DIM * DIM, dinv, xws);
    agg_kernel<<<NNODES / 4, 256, 0, stream>>>(xws, offs, csr_src, dinv, B[l],
                                               hA, l < 2 ? 1 : 0);
  }

  readout_kernel<<<(NNODES + 127) / 128, 128, 0, stream>>>(hA, batch, gmaxk, gsum);
  pack_kernel<<<64, 256, 0, stream>>>(gmaxk, gsum, out);
}